// Round 1
// 3376.479 us; speedup vs baseline: 1.4324x; 1.4324x over previous
//
#include <hip/hip_runtime.h>
#include <hip/hip_bf16.h>
#include <cmath>

// Problem constants: B=32, T=1024, J=1024, H=2048
#define BB 32
#define TT 1024
#define JJ 1024
#define HH 2048
#define MM (BB * TT)      // 32768 rows
#define MHALF (MM / 2)    // 16384

typedef short s8v __attribute__((ext_vector_type(8)));   // 8 bf16 raw
typedef float f4v __attribute__((ext_vector_type(4)));
typedef unsigned int u4v __attribute__((ext_vector_type(4)));
union ABu { u4v u; s8v v; };

// ============ exact f32 -> bf16 hi/mid/lo (w == h+m+l exactly) ============
__device__ inline void split_bf16x3(float w, unsigned short& h,
                                    unsigned short& m, unsigned short& l) {
    __hip_bfloat16 bh = __float2bfloat16(w);
    const float fh = __bfloat162float(bh);
    const float r1 = w - fh;                  // exact
    __hip_bfloat16 bm = __float2bfloat16(r1);
    const float fm = __bfloat162float(bm);
    __hip_bfloat16 bl = __float2bfloat16(r1 - fm);  // exact residual (8 bits left)
    h = *(unsigned short*)&bh; m = *(unsigned short*)&bm; l = *(unsigned short*)&bl;
}

__global__ void split_w(const float* __restrict__ W,
                        unsigned short* __restrict__ ph,
                        unsigned short* __restrict__ pm,
                        unsigned short* __restrict__ pl, int n)
{
    const int i = blockIdx.x * 256 + threadIdx.x;
    if (i >= n) return;
    split_bf16x3(W[i], ph[i], pm[i], pl[i]);
}

// ============ spike MFMA GEMM — BK=64 (UNCHANGED, proven) =================
__global__ __launch_bounds__(256) void mfma_spk_gemm(
    const unsigned char* __restrict__ S,    // [M, K/8] bit-packed spikes
    const unsigned short* __restrict__ Wh,  // [N,K] bf16 raw
    const unsigned short* __restrict__ Wm,
    const unsigned short* __restrict__ Wl,
    float* __restrict__ C, int M, int N, int K)
{
    __shared__ __align__(16) unsigned short Blds[3][2][128][32];  // 48 KB
    const int tid = threadIdx.x;
    const int wv = tid >> 6;
    const int lane = tid & 63;
    const int wm = wv >> 1, wn = wv & 1;
    const int r16 = lane & 15, quad = lane >> 4;
    const int bm = blockIdx.x * 128;
    const int bn = blockIdx.y * 128;
    const int Kb = K >> 3;

    f4v acc[4][4] = {};

    const int rl = lane >> 2, chl = lane & 3;
    size_t soff[2];
    int ldsrow[2];
#pragma unroll
    for (int i = 0; i < 2; ++i) {
        const int r = wv * 32 + i * 16 + rl;
        const int kc = (chl - (r >> 1)) & 3;
        soff[i] = (size_t)(bn + r) * K + kc * 8;   // ushort units
        ldsrow[i] = wv * 32 + i * 16;
    }

    size_t aoff[4];
#pragma unroll
    for (int ms = 0; ms < 4; ++ms)
        aoff[ms] = (size_t)(bm + wm * 64 + ms * 16 + r16) * Kb + quad;

    int bR[4], bC[4];
#pragma unroll
    for (int ns = 0; ns < 4; ++ns) {
        bR[ns] = wn * 64 + ns * 16 + r16;
        bC[ns] = ((quad + (bR[ns] >> 1)) & 3) * 8;
    }

    // preload first tile's A bytes (k-chunks kh*32: byte offset kh*4)
    unsigned int ab[2][4];
#pragma unroll
    for (int kh = 0; kh < 2; ++kh)
#pragma unroll
        for (int ms = 0; ms < 4; ++ms) ab[kh][ms] = S[aoff[ms] + kh * 4];

    for (int k0 = 0; k0 < K; k0 += 64) {
        __syncthreads();
#pragma unroll
        for (int i = 0; i < 2; ++i)
#pragma unroll
            for (int kh = 0; kh < 2; ++kh) {
                __builtin_amdgcn_global_load_lds(
                    (const __attribute__((address_space(1))) void*)(Wh + soff[i] + k0 + kh * 32),
                    (__attribute__((address_space(3))) void*)&Blds[0][kh][ldsrow[i]][0], 16, 0, 0);
                __builtin_amdgcn_global_load_lds(
                    (const __attribute__((address_space(1))) void*)(Wm + soff[i] + k0 + kh * 32),
                    (__attribute__((address_space(3))) void*)&Blds[1][kh][ldsrow[i]][0], 16, 0, 0);
                __builtin_amdgcn_global_load_lds(
                    (const __attribute__((address_space(1))) void*)(Wl + soff[i] + k0 + kh * 32),
                    (__attribute__((address_space(3))) void*)&Blds[2][kh][ldsrow[i]][0], 16, 0, 0);
            }
        // unpack current A bytes -> bf16 fragments
        s8v afr[2][4];
#pragma unroll
        for (int kh = 0; kh < 2; ++kh)
#pragma unroll
            for (int ms = 0; ms < 4; ++ms) {
                ABu t;
                const unsigned int b = ab[kh][ms];
                t.u[0] = ((b        & 1u) * 0x3F80u) | (((b >> 1) & 1u) * 0x3F800000u);
                t.u[1] = (((b >> 2) & 1u) * 0x3F80u) | (((b >> 3) & 1u) * 0x3F800000u);
                t.u[2] = (((b >> 4) & 1u) * 0x3F80u) | (((b >> 5) & 1u) * 0x3F800000u);
                t.u[3] = (((b >> 6) & 1u) * 0x3F80u) | (((b >> 7) & 1u) * 0x3F800000u);
                afr[kh][ms] = t.v;
            }
        // prefetch next tile's A bytes (global only — no LDS hazard)
        if (k0 + 64 < K) {
            const size_t kb = (size_t)((k0 + 64) >> 3);
#pragma unroll
            for (int kh = 0; kh < 2; ++kh)
#pragma unroll
                for (int ms = 0; ms < 4; ++ms) ab[kh][ms] = S[aoff[ms] + kb + kh * 4];
        }
        __syncthreads();
#pragma unroll
        for (int p = 0; p < 3; ++p)
#pragma unroll
            for (int kh = 0; kh < 2; ++kh) {
                s8v bf[4];
#pragma unroll
                for (int ns = 0; ns < 4; ++ns)
                    bf[ns] = *(const s8v*)&Blds[p][kh][bR[ns]][bC[ns]];
#pragma unroll
                for (int ms = 0; ms < 4; ++ms)
#pragma unroll
                    for (int ns = 0; ns < 4; ++ns)
                        acc[ms][ns] = __builtin_amdgcn_mfma_f32_16x16x32_bf16(
                            afr[kh][ms], bf[ns], acc[ms][ns], 0, 0, 0);
            }
    }

#pragma unroll
    for (int ms = 0; ms < 4; ++ms)
#pragma unroll
        for (int ns = 0; ns < 4; ++ns) {
            const int row = bm + wm * 64 + ms * 16 + quad * 4;
            const int col = bn + wn * 64 + ns * 16 + r16;
#pragma unroll
            for (int r = 0; r < 4; ++r)
                C[(size_t)(row + r) * N + col] = acc[ms][ns][r];
        }
}

// ============ f32 SGEMM for layer 1 (UNCHANGED — control this round) ======
#define BM 128
#define BN 128
#define BK 16
#define LDS_LD 132

__global__ __launch_bounds__(256) void sgemm_bt(
    const float* __restrict__ A,   // [M,K]
    const float* __restrict__ W,   // [N,K]
    float* __restrict__ C,         // [M,N]
    int M, int N, int K)
{
    __shared__ float As[BK][LDS_LD];
    __shared__ float Bs[BK][LDS_LD];
    const int tid = threadIdx.x;
    const int tx = tid & 15;
    const int ty = tid >> 4;
    const int bm = blockIdx.x * BM;
    const int bn = blockIdx.y * BN;

    float acc[8][8];
#pragma unroll
    for (int i = 0; i < 8; ++i)
#pragma unroll
        for (int j = 0; j < 8; ++j) acc[i][j] = 0.f;

    const int r0 = tid >> 2;
    const int c4 = (tid & 3) * 4;

    for (int k0 = 0; k0 < K; k0 += BK) {
#pragma unroll
        for (int l = 0; l < 2; ++l) {
            const int r = r0 + l * 64;
            const float4 va = *(const float4*)(A + (size_t)(bm + r) * K + k0 + c4);
            As[c4 + 0][r] = va.x; As[c4 + 1][r] = va.y;
            As[c4 + 2][r] = va.z; As[c4 + 3][r] = va.w;
            const float4 vb = *(const float4*)(W + (size_t)(bn + r) * K + k0 + c4);
            Bs[c4 + 0][r] = vb.x; Bs[c4 + 1][r] = vb.y;
            Bs[c4 + 2][r] = vb.z; Bs[c4 + 3][r] = vb.w;
        }
        __syncthreads();
#pragma unroll
        for (int k = 0; k < BK; ++k) {
            float a[8], b[8];
            *(float4*)&a[0] = *(const float4*)&As[k][ty * 8];
            *(float4*)&a[4] = *(const float4*)&As[k][ty * 8 + 4];
            *(float4*)&b[0] = *(const float4*)&Bs[k][tx * 4];
            *(float4*)&b[4] = *(const float4*)&Bs[k][64 + tx * 4];
#pragma unroll
            for (int i = 0; i < 8; ++i)
#pragma unroll
                for (int j = 0; j < 8; ++j)
                    acc[i][j] = fmaf(a[i], b[j], acc[i][j]);
        }
        __syncthreads();
    }
#pragma unroll
    for (int i = 0; i < 8; ++i) {
        const size_t row = (size_t)(bm + ty * 8 + i) * N;
        *(float4*)(C + row + bn + tx * 4)      = make_float4(acc[i][0], acc[i][1], acc[i][2], acc[i][3]);
        *(float4*)(C + row + bn + 64 + tx * 4) = make_float4(acc[i][4], acc[i][5], acc[i][6], acc[i][7]);
    }
}

// ============ BatchNorm stats — halves MERGED into one dispatch ===========
#define RCHUNK 128

__global__ void bn_stats_partial2(const float* __restrict__ hA,
                                  const float* __restrict__ hB,
                                  float* __restrict__ partial, int N)
{
    const int n = blockIdx.x * 256 + threadIdx.x;
    const int chunk = blockIdx.y;                      // 0..255 global chunk
    const int half = (MM / RCHUNK) / 2;                // 128
    const float* __restrict__ h = (chunk < half) ? hA : hB;
    const int cl = chunk & (half - 1);
    const float* p = h + (size_t)cl * RCHUNK * N + n;
    float s = 0.f, s2 = 0.f;
#pragma unroll 4
    for (int r = 0; r < RCHUNK; ++r) {
        const float v = p[(size_t)r * N];
        s += v;
        s2 = fmaf(v, v, s2);
    }
    partial[((size_t)chunk * 2 + 0) * N + n] = s;
    partial[((size_t)chunk * 2 + 1) * N + n] = s2;
}

__global__ void bn_stats_final(const float* __restrict__ partial,
                               float* __restrict__ stats,
                               int N, int nchunks)
{
    const int n = blockIdx.x * 256 + threadIdx.x;
    double s = 0.0, s2 = 0.0;
    for (int c = 0; c < nchunks; ++c) {
        s  += (double)partial[((size_t)c * 2 + 0) * N + n];
        s2 += (double)partial[((size_t)c * 2 + 1) * N + n];
    }
    const double inv_m = 1.0 / (double)MM;
    const double mu = s * inv_m;
    const double var = s2 * inv_m - mu * mu;
    stats[n]     = (float)mu;
    stats[N + n] = (float)(1.0 / sqrt(var + 1e-5));
}

// ============ fused BN + LIF scan — merged, 64-thr blocks, deep prefetch ==
// Arithmetic expressions are IDENTICAL to the proven version (bit-exact);
// only the load schedule changes: distance-24..32 register prefetch ring
// (4 named 8-float buffers, all indices compile-time constant).

// one LIF step; consumes hv, updates u/s, ballots+stores, advances widx
#define LIF_STEP_PACK(hv)                                            \
    do {                                                             \
        const float hn = ((hv) - mu) * rstd * g + bi;                \
        u = beta * (u - s) + omb * hn;                               \
        const bool sp = (u - 1.0f) >= 0.f;                           \
        s = sp ? 1.f : 0.f;                                          \
        const unsigned long long mball = __ballot(sp);               \
        if (lead) bits[widx] = mball;                                \
        widx += nw;                                                  \
    } while (0)

#define LIF_LOAD8(buf, tbase)                                        \
    _Pragma("unroll")                                                \
    for (int j = 0; j < 8; ++j) {                                    \
        const int tl = (tbase) + j;                                  \
        buf[j] = h[base + (size_t)(tl < TT ? tl : TT - 1) * N];      \
    }

__global__ __launch_bounds__(64) void bn_lif_scan_pack2(
    const float* __restrict__ hA,      // [MHALF, N]  (b < 16)
    const float* __restrict__ hB,      // [MHALF, N]  (b >= 16)
    unsigned long long* __restrict__ bits,
    const float* __restrict__ stats,
    const float* __restrict__ gamma,
    const float* __restrict__ bias,
    const float* __restrict__ beta_p,
    const float* __restrict__ U0,      // [BB, N]
    int N)
{
    const int n = blockIdx.x * 64 + threadIdx.x;
    const int b = blockIdx.y;                       // global batch 0..31
    const float* __restrict__ h = (b < BB / 2) ? hA : hB;
    const int bl = b & (BB / 2 - 1);
    const int nw = N >> 6;
    const float mu = stats[n];
    const float rstd = stats[N + n];
    const float g = gamma[n];
    const float bi = bias[n];
    const float beta = 1.f / (1.f + expf(-beta_p[n]));
    const float omb = 1.f - beta;
    float u = U0[(size_t)b * N + n];
    float s = 0.f;
    const size_t base = ((size_t)bl * TT) * N + n;
    size_t widx = ((size_t)b * TT) * nw + (n >> 6);
    const bool lead = (threadIdx.x & 63) == 0;

    float b0[8], b1[8], b2[8], b3[8];
    LIF_LOAD8(b0, 0);
    LIF_LOAD8(b1, 8);
    LIF_LOAD8(b2, 16);
    for (int t0 = 0; t0 < TT; t0 += 32) {
        LIF_LOAD8(b3, t0 + 24);
#pragma unroll
        for (int j = 0; j < 8; ++j) { const float hv = b0[j]; LIF_STEP_PACK(hv); }
        LIF_LOAD8(b0, t0 + 32);
#pragma unroll
        for (int j = 0; j < 8; ++j) { const float hv = b1[j]; LIF_STEP_PACK(hv); }
        LIF_LOAD8(b1, t0 + 40);
#pragma unroll
        for (int j = 0; j < 8; ++j) { const float hv = b2[j]; LIF_STEP_PACK(hv); }
        LIF_LOAD8(b2, t0 + 48);
#pragma unroll
        for (int j = 0; j < 8; ++j) { const float hv = b3[j]; LIF_STEP_PACK(hv); }
    }
}

#define LIF_STEP_F32(hv)                                             \
    do {                                                             \
        const float hn = ((hv) - mu) * rstd * g + bi;                \
        u = beta * (u - s) + omb * hn;                               \
        s = ((u - 1.0f) >= 0.f) ? 1.f : 0.f;                         \
        out[oidx] = s;                                               \
        oidx += N;                                                   \
    } while (0)

__global__ __launch_bounds__(64) void bn_lif_scan_f32_2(
    const float* __restrict__ h,       // [MM, N] (full)
    float* __restrict__ out,
    const float* __restrict__ stats,
    const float* __restrict__ gamma,
    const float* __restrict__ bias,
    const float* __restrict__ beta_p,
    const float* __restrict__ U0,
    int N)
{
    const int n = blockIdx.x * 64 + threadIdx.x;
    const int b = blockIdx.y;
    const float mu = stats[n];
    const float rstd = stats[N + n];
    const float g = gamma[n];
    const float bi = bias[n];
    const float beta = 1.f / (1.f + expf(-beta_p[n]));
    const float omb = 1.f - beta;
    float u = U0[(size_t)b * N + n];
    float s = 0.f;
    const size_t base = ((size_t)b * TT) * N + n;
    size_t oidx = base;

    float b0[8], b1[8], b2[8], b3[8];
    LIF_LOAD8(b0, 0);
    LIF_LOAD8(b1, 8);
    LIF_LOAD8(b2, 16);
    for (int t0 = 0; t0 < TT; t0 += 32) {
        LIF_LOAD8(b3, t0 + 24);
#pragma unroll
        for (int j = 0; j < 8; ++j) { const float hv = b0[j]; LIF_STEP_F32(hv); }
        LIF_LOAD8(b0, t0 + 32);
#pragma unroll
        for (int j = 0; j < 8; ++j) { const float hv = b1[j]; LIF_STEP_F32(hv); }
        LIF_LOAD8(b1, t0 + 40);
#pragma unroll
        for (int j = 0; j < 8; ++j) { const float hv = b2[j]; LIF_STEP_F32(hv); }
        LIF_LOAD8(b2, t0 + 48);
#pragma unroll
        for (int j = 0; j < 8; ++j) { const float hv = b3[j]; LIF_STEP_F32(hv); }
    }
}

// ============ launcher ====================================================
extern "C" void kernel_launch(void* const* d_in, const int* in_sizes, int n_in,
                              void* d_out, int out_size, void* d_ws, size_t ws_size,
                              hipStream_t stream)
{
    const float* x   = (const float*)d_in[0];
    const float* W1  = (const float*)d_in[1];
    const float* bp1 = (const float*)d_in[2];
    const float* g1  = (const float*)d_in[3];
    const float* bi1 = (const float*)d_in[4];
    const float* U01 = (const float*)d_in[5];
    const float* W2  = (const float*)d_in[6];
    const float* bp2 = (const float*)d_in[7];
    const float* g2  = (const float*)d_in[8];
    const float* bi2 = (const float*)d_in[9];
    const float* U02 = (const float*)d_in[10];
    const float* W3  = (const float*)d_in[11];
    const float* bp3 = (const float*)d_in[12];
    const float* g3  = (const float*)d_in[13];
    const float* bi3 = (const float*)d_in[14];
    const float* U03 = (const float*)d_in[15];
    float* out = (float*)d_out;

    // ws layout (unchanged, ~185 MB): hA | spk | part | stat | W2/W3 planes
    unsigned char* ws = (unsigned char*)d_ws;
    const size_t HA_BYTES  = (size_t)MHALF * HH * sizeof(float);  // 134217728
    const size_t SPK_BYTES = (size_t)MM * (HH / 8);               // 8388608
    float*              hA   = (float*)ws;
    float*              hB   = (float*)d_out;  // scratch until final scan
    unsigned long long* spk  = (unsigned long long*)(ws + HA_BYTES);
    float*              part = (float*)(ws + HA_BYTES + SPK_BYTES);
    float*              stat = (float*)(ws + HA_BYTES + SPK_BYTES + 4194304);
    unsigned short*     W2h  = (unsigned short*)(ws + HA_BYTES + SPK_BYTES + 4194304 + 16384);
    unsigned short*     W2m  = W2h + (size_t)HH * HH;
    unsigned short*     W2l  = W2m + (size_t)HH * HH;
    unsigned short*     W3h  = W2l + (size_t)HH * HH;
    unsigned short*     W3m  = W3h + (size_t)JJ * HH;
    unsigned short*     W3l  = W3m + (size_t)JJ * HH;

    const dim3 blk(256);
    const dim3 blk64(64);
    const int nck = MM / RCHUNK;       // 256 chunks (global, both halves)

    split_w<<<dim3((HH * HH) / 256), blk, 0, stream>>>(W2, W2h, W2m, W2l, HH * HH);
    split_w<<<dim3((JJ * HH) / 256), blk, 0, stream>>>(W3, W3h, W3m, W3l, JJ * HH);

    // ---- Layer 1: x[M,J] * W1[H,J]^T (f32 vector GEMM, unchanged) ----
    sgemm_bt<<<dim3(MHALF / BM, HH / BN), blk, 0, stream>>>(x, W1, hA, MHALF, HH, JJ);
    sgemm_bt<<<dim3(MHALF / BM, HH / BN), blk, 0, stream>>>(
        x + (size_t)MHALF * JJ, W1, hB, MHALF, HH, JJ);
    bn_stats_partial2<<<dim3(HH / 256, nck), blk, 0, stream>>>(hA, hB, part, HH);
    bn_stats_final<<<dim3(HH / 256), blk, 0, stream>>>(part, stat, HH, nck);
    bn_lif_scan_pack2<<<dim3(HH / 64, BB), blk64, 0, stream>>>(
        hA, hB, spk, stat, g1, bi1, bp1, U01, HH);

    // ---- Layer 2: spk[M,H] * W2[H,H]^T (MFMA bf16x3, per half) ----
    mfma_spk_gemm<<<dim3(MHALF / 128, HH / 128), blk, 0, stream>>>(
        (const unsigned char*)spk, W2h, W2m, W2l, hA, MHALF, HH, HH);
    mfma_spk_gemm<<<dim3(MHALF / 128, HH / 128), blk, 0, stream>>>(
        (const unsigned char*)spk + (size_t)MHALF * (HH / 8), W2h, W2m, W2l, hB, MHALF, HH, HH);
    bn_stats_partial2<<<dim3(HH / 256, nck), blk, 0, stream>>>(hA, hB, part, HH);
    bn_stats_final<<<dim3(HH / 256), blk, 0, stream>>>(part, stat, HH, nck);
    bn_lif_scan_pack2<<<dim3(HH / 64, BB), blk64, 0, stream>>>(
        hA, hB, spk, stat, g2, bi2, bp2, U02, HH);

    // ---- Layer 3: spk[M,H] * W3[J,H]^T -> hA [M,1024] ----
    mfma_spk_gemm<<<dim3(MM / 128, JJ / 128), blk, 0, stream>>>(
        (const unsigned char*)spk, W3h, W3m, W3l, hA, MM, JJ, HH);
    bn_stats_partial2<<<dim3(JJ / 256, nck), blk, 0, stream>>>(
        hA, hA + (size_t)MHALF * JJ, part, JJ);
    bn_stats_final<<<dim3(JJ / 256), blk, 0, stream>>>(part, stat, JJ, nck);
    bn_lif_scan_f32_2<<<dim3(JJ / 64, BB), blk64, 0, stream>>>(
        hA, out, stat, g3, bi3, bp3, U03, JJ);
}

// Round 3
// 2791.666 us; speedup vs baseline: 1.7325x; 1.2095x over previous
//
#include <hip/hip_runtime.h>
#include <hip/hip_bf16.h>
#include <cmath>

// Problem constants: B=32, T=1024, J=1024, H=2048
#define BB 32
#define TT 1024
#define JJ 1024
#define HH 2048
#define MM (BB * TT)      // 32768 rows
#define MHALF (MM / 2)    // 16384

typedef short s8v __attribute__((ext_vector_type(8)));   // 8 bf16 raw
typedef float f4v __attribute__((ext_vector_type(4)));
typedef unsigned int u4v __attribute__((ext_vector_type(4)));
union ABu { u4v u; s8v v; };

// ============ exact f32 -> bf16 hi/mid/lo (w == h+m+l exactly) ============
__device__ inline void split_bf16x3(float w, unsigned short& h,
                                    unsigned short& m, unsigned short& l) {
    __hip_bfloat16 bh = __float2bfloat16(w);
    const float fh = __bfloat162float(bh);
    const float r1 = w - fh;                  // exact
    __hip_bfloat16 bm = __float2bfloat16(r1);
    const float fm = __bfloat162float(bm);
    __hip_bfloat16 bl = __float2bfloat16(r1 - fm);  // exact residual (8 bits left)
    h = *(unsigned short*)&bh; m = *(unsigned short*)&bm; l = *(unsigned short*)&bl;
}

__global__ void split_w(const float* __restrict__ W,
                        unsigned short* __restrict__ ph,
                        unsigned short* __restrict__ pm,
                        unsigned short* __restrict__ pl, int n)
{
    const int i = blockIdx.x * 256 + threadIdx.x;
    if (i >= n) return;
    split_bf16x3(W[i], ph[i], pm[i], pl[i]);
}

// ============ spike MFMA GEMM — BK=64 (UNCHANGED, proven) =================
__global__ __launch_bounds__(256) void mfma_spk_gemm(
    const unsigned char* __restrict__ S,    // [M, K/8] bit-packed spikes
    const unsigned short* __restrict__ Wh,  // [N,K] bf16 raw
    const unsigned short* __restrict__ Wm,
    const unsigned short* __restrict__ Wl,
    float* __restrict__ C, int M, int N, int K)
{
    __shared__ __align__(16) unsigned short Blds[3][2][128][32];  // 48 KB
    const int tid = threadIdx.x;
    const int wv = tid >> 6;
    const int lane = tid & 63;
    const int wm = wv >> 1, wn = wv & 1;
    const int r16 = lane & 15, quad = lane >> 4;
    const int bm = blockIdx.x * 128;
    const int bn = blockIdx.y * 128;
    const int Kb = K >> 3;

    f4v acc[4][4] = {};

    const int rl = lane >> 2, chl = lane & 3;
    size_t soff[2];
    int ldsrow[2];
#pragma unroll
    for (int i = 0; i < 2; ++i) {
        const int r = wv * 32 + i * 16 + rl;
        const int kc = (chl - (r >> 1)) & 3;
        soff[i] = (size_t)(bn + r) * K + kc * 8;   // ushort units
        ldsrow[i] = wv * 32 + i * 16;
    }

    size_t aoff[4];
#pragma unroll
    for (int ms = 0; ms < 4; ++ms)
        aoff[ms] = (size_t)(bm + wm * 64 + ms * 16 + r16) * Kb + quad;

    int bR[4], bC[4];
#pragma unroll
    for (int ns = 0; ns < 4; ++ns) {
        bR[ns] = wn * 64 + ns * 16 + r16;
        bC[ns] = ((quad + (bR[ns] >> 1)) & 3) * 8;
    }

    // preload first tile's A bytes (k-chunks kh*32: byte offset kh*4)
    unsigned int ab[2][4];
#pragma unroll
    for (int kh = 0; kh < 2; ++kh)
#pragma unroll
        for (int ms = 0; ms < 4; ++ms) ab[kh][ms] = S[aoff[ms] + kh * 4];

    for (int k0 = 0; k0 < K; k0 += 64) {
        __syncthreads();
#pragma unroll
        for (int i = 0; i < 2; ++i)
#pragma unroll
            for (int kh = 0; kh < 2; ++kh) {
                __builtin_amdgcn_global_load_lds(
                    (const __attribute__((address_space(1))) void*)(Wh + soff[i] + k0 + kh * 32),
                    (__attribute__((address_space(3))) void*)&Blds[0][kh][ldsrow[i]][0], 16, 0, 0);
                __builtin_amdgcn_global_load_lds(
                    (const __attribute__((address_space(1))) void*)(Wm + soff[i] + k0 + kh * 32),
                    (__attribute__((address_space(3))) void*)&Blds[1][kh][ldsrow[i]][0], 16, 0, 0);
                __builtin_amdgcn_global_load_lds(
                    (const __attribute__((address_space(1))) void*)(Wl + soff[i] + k0 + kh * 32),
                    (__attribute__((address_space(3))) void*)&Blds[2][kh][ldsrow[i]][0], 16, 0, 0);
            }
        // unpack current A bytes -> bf16 fragments
        s8v afr[2][4];
#pragma unroll
        for (int kh = 0; kh < 2; ++kh)
#pragma unroll
            for (int ms = 0; ms < 4; ++ms) {
                ABu t;
                const unsigned int b = ab[kh][ms];
                t.u[0] = ((b        & 1u) * 0x3F80u) | (((b >> 1) & 1u) * 0x3F800000u);
                t.u[1] = (((b >> 2) & 1u) * 0x3F80u) | (((b >> 3) & 1u) * 0x3F800000u);
                t.u[2] = (((b >> 4) & 1u) * 0x3F80u) | (((b >> 5) & 1u) * 0x3F800000u);
                t.u[3] = (((b >> 6) & 1u) * 0x3F80u) | (((b >> 7) & 1u) * 0x3F800000u);
                afr[kh][ms] = t.v;
            }
        // prefetch next tile's A bytes (global only — no LDS hazard)
        if (k0 + 64 < K) {
            const size_t kb = (size_t)((k0 + 64) >> 3);
#pragma unroll
            for (int kh = 0; kh < 2; ++kh)
#pragma unroll
                for (int ms = 0; ms < 4; ++ms) ab[kh][ms] = S[aoff[ms] + kb + kh * 4];
        }
        __syncthreads();
#pragma unroll
        for (int p = 0; p < 3; ++p)
#pragma unroll
            for (int kh = 0; kh < 2; ++kh) {
                s8v bf[4];
#pragma unroll
                for (int ns = 0; ns < 4; ++ns)
                    bf[ns] = *(const s8v*)&Blds[p][kh][bR[ns]][bC[ns]];
#pragma unroll
                for (int ms = 0; ms < 4; ++ms)
#pragma unroll
                    for (int ns = 0; ns < 4; ++ns)
                        acc[ms][ns] = __builtin_amdgcn_mfma_f32_16x16x32_bf16(
                            afr[kh][ms], bf[ns], acc[ms][ns], 0, 0, 0);
            }
    }

#pragma unroll
    for (int ms = 0; ms < 4; ++ms)
#pragma unroll
        for (int ns = 0; ns < 4; ++ns) {
            const int row = bm + wm * 64 + ms * 16 + quad * 4;
            const int col = bn + wn * 64 + ns * 16 + r16;
#pragma unroll
            for (int r = 0; r < 4; ++r)
                C[(size_t)(row + r) * N + col] = acc[ms][ns][r];
        }
}

// ============ f32-via-bf16x3 MFMA GEMM for layer 1 ========================
// C[M,N] = A[M,K](f32) @ W[N,K]^T. W pre-split into 3 RNE bf16 planes
// (exact). A split IN-REGISTER by exact truncation: a0 = x&0xFFFF0000,
// r1 = x-a0 (exact), a1 = trunc(r1), a2 = r1-a1 (exact, fits bf16).
// 6 product terms kept: a0w0,a0w1,a1w0,a0w2,a1w1,a2w0 — dropped terms
// (a1w2,a2w1,a2w2) are <=2^-25 relative, below f32 accumulation noise.
struct Sp3 { unsigned int o0, o1, o2; };

__device__ inline Sp3 split_pair(float x, float y)
{
    const unsigned int xb = __float_as_uint(x), yb = __float_as_uint(y);
    const unsigned int x0 = xb & 0xFFFF0000u,  y0 = yb & 0xFFFF0000u;
    const float xr1 = x - __uint_as_float(x0), yr1 = y - __uint_as_float(y0);
    const unsigned int x1b = __float_as_uint(xr1), y1b = __float_as_uint(yr1);
    const unsigned int x1 = x1b & 0xFFFF0000u, y1 = y1b & 0xFFFF0000u;
    const float xr2 = xr1 - __uint_as_float(x1), yr2 = yr1 - __uint_as_float(y1);
    Sp3 r;
    // pack bf16 pair (x in low16, y in high16) = bytes [x.b2,x.b3,y.b2,y.b3]
    r.o0 = __builtin_amdgcn_perm(yb, xb, 0x07060302u);
    r.o1 = __builtin_amdgcn_perm(y1b, x1b, 0x07060302u);
    r.o2 = __builtin_amdgcn_perm(__float_as_uint(yr2), __float_as_uint(xr2), 0x07060302u);
    return r;
}

__global__ __launch_bounds__(256) void mfma_f32x3_gemm(
    const float* __restrict__ A,            // [M,K] f32
    const unsigned short* __restrict__ Wh,  // [N,K] bf16 planes (exact sum)
    const unsigned short* __restrict__ Wm,
    const unsigned short* __restrict__ Wl,
    float* __restrict__ C, int M, int N, int K)
{
    __shared__ __align__(16) unsigned short Blds[3][2][128][32];  // 48 KB
    const int tid = threadIdx.x;
    const int wv = tid >> 6;
    const int lane = tid & 63;
    const int wm = wv >> 1, wn = wv & 1;
    const int r16 = lane & 15, quad = lane >> 4;

    // XCD-chunked panel swizzle: gridDim.x == 16 (N-tiles), gridDim.y = M-tiles
    // (divisible by 8). All 16 N-blocks of an M-panel land on ONE XCD and are
    // temporally adjacent -> A-panel (512 KB) is read ~once into that L2.
    const int lin = blockIdx.y * 16 + blockIdx.x;   // dispatch-order index
    const int ppx = gridDim.y >> 3;                 // M-panels per XCD
    const int xcd = lin & 7, li = lin >> 3;
    const int pm = xcd * ppx + (li >> 4);
    const int pn = li & 15;
    const int bm = pm * 128;
    const int bn = pn * 128;

    f4v acc[4][4] = {};

    const int rl = lane >> 2, chl = lane & 3;
    size_t soff[2];
    int ldsrow[2];
#pragma unroll
    for (int i = 0; i < 2; ++i) {
        const int r = wv * 32 + i * 16 + rl;
        const int kc = (chl - (r >> 1)) & 3;
        soff[i] = (size_t)(bn + r) * K + kc * 8;   // ushort units
        ldsrow[i] = wv * 32 + i * 16;
    }

    size_t aoff[4];
#pragma unroll
    for (int ms = 0; ms < 4; ++ms)
        aoff[ms] = (size_t)(bm + wm * 64 + ms * 16 + r16) * K + quad * 8;  // f32 units

    int bR[4], bC[4];
#pragma unroll
    for (int ns = 0; ns < 4; ++ns) {
        bR[ns] = wn * 64 + ns * 16 + r16;
        bC[ns] = ((quad + (bR[ns] >> 1)) & 3) * 8;
    }

    // prologue: load first tile's A f32 (8 elems per (kh,ms) = 2 float4)
    float4 av[2][4][2];
#pragma unroll
    for (int kh = 0; kh < 2; ++kh)
#pragma unroll
        for (int ms = 0; ms < 4; ++ms) {
            av[kh][ms][0] = *(const float4*)(A + aoff[ms] + kh * 32);
            av[kh][ms][1] = *(const float4*)(A + aoff[ms] + kh * 32 + 4);
        }

    for (int k0 = 0; k0 < K; k0 += 64) {
        __syncthreads();
        // stage W planes for this K-tile (proven swizzle, direct-to-LDS)
#pragma unroll
        for (int i = 0; i < 2; ++i)
#pragma unroll
            for (int kh = 0; kh < 2; ++kh) {
                __builtin_amdgcn_global_load_lds(
                    (const __attribute__((address_space(1))) void*)(Wh + soff[i] + k0 + kh * 32),
                    (__attribute__((address_space(3))) void*)&Blds[0][kh][ldsrow[i]][0], 16, 0, 0);
                __builtin_amdgcn_global_load_lds(
                    (const __attribute__((address_space(1))) void*)(Wm + soff[i] + k0 + kh * 32),
                    (__attribute__((address_space(3))) void*)&Blds[1][kh][ldsrow[i]][0], 16, 0, 0);
                __builtin_amdgcn_global_load_lds(
                    (const __attribute__((address_space(1))) void*)(Wl + soff[i] + k0 + kh * 32),
                    (__attribute__((address_space(3))) void*)&Blds[2][kh][ldsrow[i]][0], 16, 0, 0);
            }
        // split current A f32 -> 3 bf16 plane fragments (register-only)
        s8v afr[3][2][4];
#pragma unroll
        for (int kh = 0; kh < 2; ++kh)
#pragma unroll
            for (int ms = 0; ms < 4; ++ms) {
                ABu t0, t1, t2;
                const float4 v0 = av[kh][ms][0];
                const float4 v1 = av[kh][ms][1];
                const Sp3 s0 = split_pair(v0.x, v0.y);
                const Sp3 s1 = split_pair(v0.z, v0.w);
                const Sp3 s2 = split_pair(v1.x, v1.y);
                const Sp3 s3 = split_pair(v1.z, v1.w);
                t0.u[0] = s0.o0; t1.u[0] = s0.o1; t2.u[0] = s0.o2;
                t0.u[1] = s1.o0; t1.u[1] = s1.o1; t2.u[1] = s1.o2;
                t0.u[2] = s2.o0; t1.u[2] = s2.o1; t2.u[2] = s2.o2;
                t0.u[3] = s3.o0; t1.u[3] = s3.o1; t2.u[3] = s3.o2;
                afr[0][kh][ms] = t0.v;
                afr[1][kh][ms] = t1.v;
                afr[2][kh][ms] = t2.v;
            }
        __syncthreads();
        // prefetch next tile's A f32 (issued before long MFMA phase; the
        // latency hides under the MFMAs, drained by next iter's barrier)
        if (k0 + 64 < K) {
#pragma unroll
            for (int kh = 0; kh < 2; ++kh)
#pragma unroll
                for (int ms = 0; ms < 4; ++ms) {
                    av[kh][ms][0] = *(const float4*)(A + aoff[ms] + k0 + 64 + kh * 32);
                    av[kh][ms][1] = *(const float4*)(A + aoff[ms] + k0 + 64 + kh * 32 + 4);
                }
        }
        // 6-term MFMA: w-plane outer (one B-frag read per (pw,kh)),
        // a-planes with pa+pw<3 inner
#pragma unroll
        for (int kh = 0; kh < 2; ++kh)
#pragma unroll
            for (int pw = 0; pw < 3; ++pw) {
                s8v bf[4];
#pragma unroll
                for (int ns = 0; ns < 4; ++ns)
                    bf[ns] = *(const s8v*)&Blds[pw][kh][bR[ns]][bC[ns]];
#pragma unroll
                for (int pa = 0; pa + pw < 3; ++pa)
#pragma unroll
                    for (int ms = 0; ms < 4; ++ms)
#pragma unroll
                        for (int ns = 0; ns < 4; ++ns)
                            acc[ms][ns] = __builtin_amdgcn_mfma_f32_16x16x32_bf16(
                                afr[pa][kh][ms], bf[ns], acc[ms][ns], 0, 0, 0);
            }
    }

#pragma unroll
    for (int ms = 0; ms < 4; ++ms)
#pragma unroll
        for (int ns = 0; ns < 4; ++ns) {
            const int row = bm + wm * 64 + ms * 16 + quad * 4;
            const int col = bn + wn * 64 + ns * 16 + r16;
#pragma unroll
            for (int r = 0; r < 4; ++r)
                C[(size_t)(row + r) * N + col] = acc[ms][ns][r];
        }
}

// ============ BatchNorm stats — halves MERGED into one dispatch ===========
#define RCHUNK 128

__global__ void bn_stats_partial2(const float* __restrict__ hA,
                                  const float* __restrict__ hB,
                                  float* __restrict__ partial, int N)
{
    const int n = blockIdx.x * 256 + threadIdx.x;
    const int chunk = blockIdx.y;                      // 0..255 global chunk
    const int half = (MM / RCHUNK) / 2;                // 128
    const float* __restrict__ h = (chunk < half) ? hA : hB;
    const int cl = chunk & (half - 1);
    const float* p = h + (size_t)cl * RCHUNK * N + n;
    float s = 0.f, s2 = 0.f;
#pragma unroll 4
    for (int r = 0; r < RCHUNK; ++r) {
        const float v = p[(size_t)r * N];
        s += v;
        s2 = fmaf(v, v, s2);
    }
    partial[((size_t)chunk * 2 + 0) * N + n] = s;
    partial[((size_t)chunk * 2 + 1) * N + n] = s2;
}

__global__ void bn_stats_final(const float* __restrict__ partial,
                               float* __restrict__ stats,
                               int N, int nchunks)
{
    const int n = blockIdx.x * 256 + threadIdx.x;
    double s = 0.0, s2 = 0.0;
    for (int c = 0; c < nchunks; ++c) {
        s  += (double)partial[((size_t)c * 2 + 0) * N + n];
        s2 += (double)partial[((size_t)c * 2 + 1) * N + n];
    }
    const double inv_m = 1.0 / (double)MM;
    const double mu = s * inv_m;
    const double var = s2 * inv_m - mu * mu;
    stats[n]     = (float)mu;
    stats[N + n] = (float)(1.0 / sqrt(var + 1e-5));
}

// ============ fused BN + LIF scan (proven R1 versions) ====================
#define LIF_STEP_PACK(hv)                                            \
    do {                                                             \
        const float hn = ((hv) - mu) * rstd * g + bi;                \
        u = beta * (u - s) + omb * hn;                               \
        const bool sp = (u - 1.0f) >= 0.f;                           \
        s = sp ? 1.f : 0.f;                                          \
        const unsigned long long mball = __ballot(sp);               \
        if (lead) bits[widx] = mball;                                \
        widx += nw;                                                  \
    } while (0)

#define LIF_LOAD8(buf, tbase)                                        \
    _Pragma("unroll")                                                \
    for (int j = 0; j < 8; ++j) {                                    \
        const int tl = (tbase) + j;                                  \
        buf[j] = h[base + (size_t)(tl < TT ? tl : TT - 1) * N];      \
    }

__global__ __launch_bounds__(64) void bn_lif_scan_pack2(
    const float* __restrict__ hA,      // [MHALF, N]  (b < 16)
    const float* __restrict__ hB,      // [MHALF, N]  (b >= 16)
    unsigned long long* __restrict__ bits,
    const float* __restrict__ stats,
    const float* __restrict__ gamma,
    const float* __restrict__ bias,
    const float* __restrict__ beta_p,
    const float* __restrict__ U0,      // [BB, N]
    int N)
{
    const int n = blockIdx.x * 64 + threadIdx.x;
    const int b = blockIdx.y;                       // global batch 0..31
    const float* __restrict__ h = (b < BB / 2) ? hA : hB;
    const int bl = b & (BB / 2 - 1);
    const int nw = N >> 6;
    const float mu = stats[n];
    const float rstd = stats[N + n];
    const float g = gamma[n];
    const float bi = bias[n];
    const float beta = 1.f / (1.f + expf(-beta_p[n]));
    const float omb = 1.f - beta;
    float u = U0[(size_t)b * N + n];
    float s = 0.f;
    const size_t base = ((size_t)bl * TT) * N + n;
    size_t widx = ((size_t)b * TT) * nw + (n >> 6);
    const bool lead = (threadIdx.x & 63) == 0;

    float b0[8], b1[8], b2[8], b3[8];
    LIF_LOAD8(b0, 0);
    LIF_LOAD8(b1, 8);
    LIF_LOAD8(b2, 16);
    for (int t0 = 0; t0 < TT; t0 += 32) {
        LIF_LOAD8(b3, t0 + 24);
#pragma unroll
        for (int j = 0; j < 8; ++j) { const float hv = b0[j]; LIF_STEP_PACK(hv); }
        LIF_LOAD8(b0, t0 + 32);
#pragma unroll
        for (int j = 0; j < 8; ++j) { const float hv = b1[j]; LIF_STEP_PACK(hv); }
        LIF_LOAD8(b1, t0 + 40);
#pragma unroll
        for (int j = 0; j < 8; ++j) { const float hv = b2[j]; LIF_STEP_PACK(hv); }
        LIF_LOAD8(b2, t0 + 48);
#pragma unroll
        for (int j = 0; j < 8; ++j) { const float hv = b3[j]; LIF_STEP_PACK(hv); }
    }
}

#define LIF_STEP_F32(hv)                                             \
    do {                                                             \
        const float hn = ((hv) - mu) * rstd * g + bi;                \
        u = beta * (u - s) + omb * hn;                               \
        s = ((u - 1.0f) >= 0.f) ? 1.f : 0.f;                         \
        out[oidx] = s;                                               \
        oidx += N;                                                   \
    } while (0)

__global__ __launch_bounds__(64) void bn_lif_scan_f32_2(
    const float* __restrict__ h,       // [MM, N] (full)
    float* __restrict__ out,
    const float* __restrict__ stats,
    const float* __restrict__ gamma,
    const float* __restrict__ bias,
    const float* __restrict__ beta_p,
    const float* __restrict__ U0,
    int N)
{
    const int n = blockIdx.x * 64 + threadIdx.x;
    const int b = blockIdx.y;
    const float mu = stats[n];
    const float rstd = stats[N + n];
    const float g = gamma[n];
    const float bi = bias[n];
    const float beta = 1.f / (1.f + expf(-beta_p[n]));
    const float omb = 1.f - beta;
    float u = U0[(size_t)b * N + n];
    float s = 0.f;
    const size_t base = ((size_t)b * TT) * N + n;
    size_t oidx = base;

    float b0[8], b1[8], b2[8], b3[8];
    LIF_LOAD8(b0, 0);
    LIF_LOAD8(b1, 8);
    LIF_LOAD8(b2, 16);
    for (int t0 = 0; t0 < TT; t0 += 32) {
        LIF_LOAD8(b3, t0 + 24);
#pragma unroll
        for (int j = 0; j < 8; ++j) { const float hv = b0[j]; LIF_STEP_F32(hv); }
        LIF_LOAD8(b0, t0 + 32);
#pragma unroll
        for (int j = 0; j < 8; ++j) { const float hv = b1[j]; LIF_STEP_F32(hv); }
        LIF_LOAD8(b1, t0 + 40);
#pragma unroll
        for (int j = 0; j < 8; ++j) { const float hv = b2[j]; LIF_STEP_F32(hv); }
        LIF_LOAD8(b2, t0 + 48);
#pragma unroll
        for (int j = 0; j < 8; ++j) { const float hv = b3[j]; LIF_STEP_F32(hv); }
    }
}

// ============ launcher ====================================================
extern "C" void kernel_launch(void* const* d_in, const int* in_sizes, int n_in,
                              void* d_out, int out_size, void* d_ws, size_t ws_size,
                              hipStream_t stream)
{
    const float* x   = (const float*)d_in[0];
    const float* W1  = (const float*)d_in[1];
    const float* bp1 = (const float*)d_in[2];
    const float* g1  = (const float*)d_in[3];
    const float* bi1 = (const float*)d_in[4];
    const float* U01 = (const float*)d_in[5];
    const float* W2  = (const float*)d_in[6];
    const float* bp2 = (const float*)d_in[7];
    const float* g2  = (const float*)d_in[8];
    const float* bi2 = (const float*)d_in[9];
    const float* U02 = (const float*)d_in[10];
    const float* W3  = (const float*)d_in[11];
    const float* bp3 = (const float*)d_in[12];
    const float* g3  = (const float*)d_in[13];
    const float* bi3 = (const float*)d_in[14];
    const float* U03 = (const float*)d_in[15];
    float* out = (float*)d_out;

    // ws layout (unchanged, ~185 MB): hA | spk | part | stat | W2/W3 planes
    // W1's 3 planes (2M ushorts each) transiently live in the W2h/W2m/W2l
    // slots (4M ushorts each) and are overwritten by split_w(W2) AFTER the
    // layer-1 GEMMs complete — sequential stream, no extra workspace.
    unsigned char* ws = (unsigned char*)d_ws;
    const size_t HA_BYTES  = (size_t)MHALF * HH * sizeof(float);  // 134217728
    const size_t SPK_BYTES = (size_t)MM * (HH / 8);               // 8388608
    float*              hA   = (float*)ws;
    float*              hB   = (float*)d_out;  // scratch until final scan
    unsigned long long* spk  = (unsigned long long*)(ws + HA_BYTES);
    float*              part = (float*)(ws + HA_BYTES + SPK_BYTES);
    float*              stat = (float*)(ws + HA_BYTES + SPK_BYTES + 4194304);
    unsigned short*     W2h  = (unsigned short*)(ws + HA_BYTES + SPK_BYTES + 4194304 + 16384);
    unsigned short*     W2m  = W2h + (size_t)HH * HH;
    unsigned short*     W2l  = W2m + (size_t)HH * HH;
    unsigned short*     W3h  = W2l + (size_t)HH * HH;
    unsigned short*     W3m  = W3h + (size_t)JJ * HH;
    unsigned short*     W3l  = W3m + (size_t)JJ * HH;

    const dim3 blk(256);
    const dim3 blk64(64);
    const int nck = MM / RCHUNK;       // 256 chunks (global, both halves)

    // ---- Layer 1: x[M,J](f32) * W1[H,J]^T via 6-term bf16x3 MFMA ----
    split_w<<<dim3((HH * JJ) / 256), blk, 0, stream>>>(W1, W2h, W2m, W2l, HH * JJ);
    mfma_f32x3_gemm<<<dim3(HH / 128, MHALF / 128), blk, 0, stream>>>(
        x, W2h, W2m, W2l, hA, MHALF, HH, JJ);
    mfma_f32x3_gemm<<<dim3(HH / 128, MHALF / 128), blk, 0, stream>>>(
        x + (size_t)MHALF * JJ, W2h, W2m, W2l, hB, MHALF, HH, JJ);
    // now W1 planes are dead — split W2/W3 into their home slots
    split_w<<<dim3((HH * HH) / 256), blk, 0, stream>>>(W2, W2h, W2m, W2l, HH * HH);
    split_w<<<dim3((JJ * HH) / 256), blk, 0, stream>>>(W3, W3h, W3m, W3l, JJ * HH);

    bn_stats_partial2<<<dim3(HH / 256, nck), blk, 0, stream>>>(hA, hB, part, HH);
    bn_stats_final<<<dim3(HH / 256), blk, 0, stream>>>(part, stat, HH, nck);
    bn_lif_scan_pack2<<<dim3(HH / 64, BB), blk64, 0, stream>>>(
        hA, hB, spk, stat, g1, bi1, bp1, U01, HH);

    // ---- Layer 2: spk[M,H] * W2[H,H]^T (MFMA bf16x3, per half) ----
    mfma_spk_gemm<<<dim3(MHALF / 128, HH / 128), blk, 0, stream>>>(
        (const unsigned char*)spk, W2h, W2m, W2l, hA, MHALF, HH, HH);
    mfma_spk_gemm<<<dim3(MHALF / 128, HH / 128), blk, 0, stream>>>(
        (const unsigned char*)spk + (size_t)MHALF * (HH / 8), W2h, W2m, W2l, hB, MHALF, HH, HH);
    bn_stats_partial2<<<dim3(HH / 256, nck), blk, 0, stream>>>(hA, hB, part, HH);
    bn_stats_final<<<dim3(HH / 256), blk, 0, stream>>>(part, stat, HH, nck);
    bn_lif_scan_pack2<<<dim3(HH / 64, BB), blk64, 0, stream>>>(
        hA, hB, spk, stat, g2, bi2, bp2, U02, HH);

    // ---- Layer 3: spk[M,H] * W3[J,H]^T -> hA [M,1024] ----
    mfma_spk_gemm<<<dim3(MM / 128, JJ / 128), blk, 0, stream>>>(
        (const unsigned char*)spk, W3h, W3m, W3l, hA, MM, JJ, HH);
    bn_stats_partial2<<<dim3(JJ / 256, nck), blk, 0, stream>>>(
        hA, hA + (size_t)MHALF * JJ, part, JJ);
    bn_stats_final<<<dim3(JJ / 256), blk, 0, stream>>>(part, stat, JJ, nck);
    bn_lif_scan_f32_2<<<dim3(JJ / 64, BB), blk64, 0, stream>>>(
        hA, out, stat, g3, bi3, bp3, U03, JJ);
}

// Round 4
// 2702.860 us; speedup vs baseline: 1.7894x; 1.0329x over previous
//
#include <hip/hip_runtime.h>
#include <hip/hip_bf16.h>
#include <cmath>

// Problem constants: B=32, T=1024, J=1024, H=2048
#define BB 32
#define TT 1024
#define JJ 1024
#define HH 2048
#define MM (BB * TT)      // 32768 rows
#define MHALF (MM / 2)    // 16384

typedef short s8v __attribute__((ext_vector_type(8)));   // 8 bf16 raw
typedef float f4v __attribute__((ext_vector_type(4)));
typedef unsigned int u4v __attribute__((ext_vector_type(4)));
union ABu { u4v u; s8v v; };

// ============ exact f32 -> bf16 hi/mid/lo (w == h+m+l exactly) ============
__device__ inline void split_bf16x3(float w, unsigned short& h,
                                    unsigned short& m, unsigned short& l) {
    __hip_bfloat16 bh = __float2bfloat16(w);
    const float fh = __bfloat162float(bh);
    const float r1 = w - fh;                  // exact
    __hip_bfloat16 bm = __float2bfloat16(r1);
    const float fm = __bfloat162float(bm);
    __hip_bfloat16 bl = __float2bfloat16(r1 - fm);  // exact residual (8 bits left)
    h = *(unsigned short*)&bh; m = *(unsigned short*)&bm; l = *(unsigned short*)&bl;
}

__global__ void split_w(const float* __restrict__ W,
                        unsigned short* __restrict__ ph,
                        unsigned short* __restrict__ pm,
                        unsigned short* __restrict__ pl, int n)
{
    const int i = blockIdx.x * 256 + threadIdx.x;
    if (i >= n) return;
    split_bf16x3(W[i], ph[i], pm[i], pl[i]);
}

// ============ spike MFMA GEMM — NEW: 256x128 tile, 8 waves, dbuf BK=64 ====
// Double-buffered B-LDS (2 x 3 planes x 2 kh x 128 x 32 halves = 96 KB).
// ONE __syncthreads per K-step; next-tile global_load_lds issued inside the
// 6 MFMA phases (1 per phase) -> staging latency hides under ~96 MFMAs and
// is drained by the NEXT K-step's barrier, never mid-compute.
__global__ __launch_bounds__(512) void mfma_spk_gemm(
    const unsigned char* __restrict__ S,    // [M, K/8] bit-packed spikes
    const unsigned short* __restrict__ Wh,  // [N,K] bf16 raw
    const unsigned short* __restrict__ Wm,
    const unsigned short* __restrict__ Wl,
    float* __restrict__ C, int M, int N, int K)
{
    __shared__ __align__(16) unsigned short Blds[2][3][2][128][32];  // 96 KB
    const int tid = threadIdx.x;
    const int wv = tid >> 6;                 // 0..7
    const int lane = tid & 63;
    const int wm = wv >> 1, wn = wv & 1;     // wm 0..3 (M), wn 0..1 (N)
    const int r16 = lane & 15, quad = lane >> 4;
    const int bm = blockIdx.x * 256;
    const int bn = blockIdx.y * 128;
    const int Kb = K >> 3;

    f4v acc[4][4] = {};

    // staging map: 8 waves x 16 rows = 128 rows per (plane,kh) load
    const int rl = lane >> 2, chl = lane & 3;
    const int srow = wv * 16 + rl;                       // 0..127
    const int kc = (chl - (srow >> 1)) & 3;
    const size_t soff = (size_t)(bn + srow) * K + kc * 8;  // ushort units
    const int ldsrow = wv * 16;

    size_t aoff[4];
#pragma unroll
    for (int ms = 0; ms < 4; ++ms)
        aoff[ms] = (size_t)(bm + wm * 64 + ms * 16 + r16) * Kb + quad;

    int bR[4], bC[4];
#pragma unroll
    for (int ns = 0; ns < 4; ++ns) {
        bR[ns] = wn * 64 + ns * 16 + r16;
        bC[ns] = ((quad + (bR[ns] >> 1)) & 3) * 8;
    }

    auto stage = [&](int buf, int p, int kh, int k0) {
        const unsigned short* Wp = (p == 0) ? Wh : (p == 1) ? Wm : Wl;
        __builtin_amdgcn_global_load_lds(
            (const __attribute__((address_space(1))) void*)(Wp + soff + k0 + kh * 32),
            (__attribute__((address_space(3))) void*)&Blds[buf][p][kh][ldsrow][0], 16, 0, 0);
    };

    // preload first tile's A bytes (k-chunks kh*32: byte offset kh*4)
    unsigned int ab[2][4];
#pragma unroll
    for (int kh = 0; kh < 2; ++kh)
#pragma unroll
        for (int ms = 0; ms < 4; ++ms) ab[kh][ms] = S[aoff[ms] + kh * 4];

    // prologue: stage tile 0 into buffer 0 (6 loads)
#pragma unroll
    for (int p = 0; p < 3; ++p)
#pragma unroll
        for (int kh = 0; kh < 2; ++kh) stage(0, p, kh, 0);

    const int NT = K >> 6;
    for (int t = 0; t < NT; ++t) {
        const int cur = t & 1, nxt = cur ^ 1;
        const int k0 = t << 6;
        __syncthreads();   // drains buf[cur] stagings (issued a full phase ago)

        // unpack current A bytes -> bf16 fragments (register-only)
        s8v afr[2][4];
#pragma unroll
        for (int kh = 0; kh < 2; ++kh)
#pragma unroll
            for (int ms = 0; ms < 4; ++ms) {
                ABu tu;
                const unsigned int b = ab[kh][ms];
                tu.u[0] = ((b        & 1u) * 0x3F80u) | (((b >> 1) & 1u) * 0x3F800000u);
                tu.u[1] = (((b >> 2) & 1u) * 0x3F80u) | (((b >> 3) & 1u) * 0x3F800000u);
                tu.u[2] = (((b >> 4) & 1u) * 0x3F80u) | (((b >> 5) & 1u) * 0x3F800000u);
                tu.u[3] = (((b >> 6) & 1u) * 0x3F80u) | (((b >> 7) & 1u) * 0x3F800000u);
                afr[kh][ms] = tu.v;
            }
        // prefetch next tile's A bytes (registers; drained by next barrier)
        if (t + 1 < NT) {
            const size_t kb = (size_t)((k0 + 64) >> 3);
#pragma unroll
            for (int kh = 0; kh < 2; ++kh)
#pragma unroll
                for (int ms = 0; ms < 4; ++ms) ab[kh][ms] = S[aoff[ms] + kb + kh * 4];
        }

        // 6 phases: {4 ds_read_b128 | 1 next-tile global_load_lds | 16 MFMA}
#pragma unroll
        for (int p = 0; p < 3; ++p)
#pragma unroll
            for (int kh = 0; kh < 2; ++kh) {
                s8v bf[4];
#pragma unroll
                for (int ns = 0; ns < 4; ++ns)
                    bf[ns] = *(const s8v*)&Blds[cur][p][kh][bR[ns]][bC[ns]];
                if (t + 1 < NT) stage(nxt, p, kh, k0 + 64);
                __builtin_amdgcn_s_setprio(1);
#pragma unroll
                for (int ms = 0; ms < 4; ++ms)
#pragma unroll
                    for (int ns = 0; ns < 4; ++ns)
                        acc[ms][ns] = __builtin_amdgcn_mfma_f32_16x16x32_bf16(
                            afr[kh][ms], bf[ns], acc[ms][ns], 0, 0, 0);
                __builtin_amdgcn_s_setprio(0);
            }
    }

#pragma unroll
    for (int ms = 0; ms < 4; ++ms)
#pragma unroll
        for (int ns = 0; ns < 4; ++ns) {
            const int row = bm + wm * 64 + ms * 16 + quad * 4;
            const int col = bn + wn * 64 + ns * 16 + r16;
#pragma unroll
            for (int r = 0; r < 4; ++r)
                C[(size_t)(row + r) * N + col] = acc[ms][ns][r];
        }
}

// ============ f32-via-bf16x3 MFMA GEMM for layer 1 (UNCHANGED — control) ==
struct Sp3 { unsigned int o0, o1, o2; };

__device__ inline Sp3 split_pair(float x, float y)
{
    const unsigned int xb = __float_as_uint(x), yb = __float_as_uint(y);
    const unsigned int x0 = xb & 0xFFFF0000u,  y0 = yb & 0xFFFF0000u;
    const float xr1 = x - __uint_as_float(x0), yr1 = y - __uint_as_float(y0);
    const unsigned int x1b = __float_as_uint(xr1), y1b = __float_as_uint(yr1);
    const unsigned int x1 = x1b & 0xFFFF0000u, y1 = y1b & 0xFFFF0000u;
    const float xr2 = xr1 - __uint_as_float(x1), yr2 = yr1 - __uint_as_float(y1);
    Sp3 r;
    // pack bf16 pair (x in low16, y in high16) = bytes [x.b2,x.b3,y.b2,y.b3]
    r.o0 = __builtin_amdgcn_perm(yb, xb, 0x07060302u);
    r.o1 = __builtin_amdgcn_perm(y1b, x1b, 0x07060302u);
    r.o2 = __builtin_amdgcn_perm(__float_as_uint(yr2), __float_as_uint(xr2), 0x07060302u);
    return r;
}

__global__ __launch_bounds__(256) void mfma_f32x3_gemm(
    const float* __restrict__ A,            // [M,K] f32
    const unsigned short* __restrict__ Wh,  // [N,K] bf16 planes (exact sum)
    const unsigned short* __restrict__ Wm,
    const unsigned short* __restrict__ Wl,
    float* __restrict__ C, int M, int N, int K)
{
    __shared__ __align__(16) unsigned short Blds[3][2][128][32];  // 48 KB
    const int tid = threadIdx.x;
    const int wv = tid >> 6;
    const int lane = tid & 63;
    const int wm = wv >> 1, wn = wv & 1;
    const int r16 = lane & 15, quad = lane >> 4;

    // XCD-chunked panel swizzle: gridDim.x == 16 (N-tiles), gridDim.y = M-tiles
    const int lin = blockIdx.y * 16 + blockIdx.x;   // dispatch-order index
    const int ppx = gridDim.y >> 3;                 // M-panels per XCD
    const int xcd = lin & 7, li = lin >> 3;
    const int pm = xcd * ppx + (li >> 4);
    const int pn = li & 15;
    const int bm = pm * 128;
    const int bn = pn * 128;

    f4v acc[4][4] = {};

    const int rl = lane >> 2, chl = lane & 3;
    size_t soff[2];
    int ldsrow[2];
#pragma unroll
    for (int i = 0; i < 2; ++i) {
        const int r = wv * 32 + i * 16 + rl;
        const int kc = (chl - (r >> 1)) & 3;
        soff[i] = (size_t)(bn + r) * K + kc * 8;   // ushort units
        ldsrow[i] = wv * 32 + i * 16;
    }

    size_t aoff[4];
#pragma unroll
    for (int ms = 0; ms < 4; ++ms)
        aoff[ms] = (size_t)(bm + wm * 64 + ms * 16 + r16) * K + quad * 8;  // f32 units

    int bR[4], bC[4];
#pragma unroll
    for (int ns = 0; ns < 4; ++ns) {
        bR[ns] = wn * 64 + ns * 16 + r16;
        bC[ns] = ((quad + (bR[ns] >> 1)) & 3) * 8;
    }

    // prologue: load first tile's A f32 (8 elems per (kh,ms) = 2 float4)
    float4 av[2][4][2];
#pragma unroll
    for (int kh = 0; kh < 2; ++kh)
#pragma unroll
        for (int ms = 0; ms < 4; ++ms) {
            av[kh][ms][0] = *(const float4*)(A + aoff[ms] + kh * 32);
            av[kh][ms][1] = *(const float4*)(A + aoff[ms] + kh * 32 + 4);
        }

    for (int k0 = 0; k0 < K; k0 += 64) {
        __syncthreads();
        // stage W planes for this K-tile (proven swizzle, direct-to-LDS)
#pragma unroll
        for (int i = 0; i < 2; ++i)
#pragma unroll
            for (int kh = 0; kh < 2; ++kh) {
                __builtin_amdgcn_global_load_lds(
                    (const __attribute__((address_space(1))) void*)(Wh + soff[i] + k0 + kh * 32),
                    (__attribute__((address_space(3))) void*)&Blds[0][kh][ldsrow[i]][0], 16, 0, 0);
                __builtin_amdgcn_global_load_lds(
                    (const __attribute__((address_space(1))) void*)(Wm + soff[i] + k0 + kh * 32),
                    (__attribute__((address_space(3))) void*)&Blds[1][kh][ldsrow[i]][0], 16, 0, 0);
                __builtin_amdgcn_global_load_lds(
                    (const __attribute__((address_space(1))) void*)(Wl + soff[i] + k0 + kh * 32),
                    (__attribute__((address_space(3))) void*)&Blds[2][kh][ldsrow[i]][0], 16, 0, 0);
            }
        // split current A f32 -> 3 bf16 plane fragments (register-only)
        s8v afr[3][2][4];
#pragma unroll
        for (int kh = 0; kh < 2; ++kh)
#pragma unroll
            for (int ms = 0; ms < 4; ++ms) {
                ABu t0, t1, t2;
                const float4 v0 = av[kh][ms][0];
                const float4 v1 = av[kh][ms][1];
                const Sp3 s0 = split_pair(v0.x, v0.y);
                const Sp3 s1 = split_pair(v0.z, v0.w);
                const Sp3 s2 = split_pair(v1.x, v1.y);
                const Sp3 s3 = split_pair(v1.z, v1.w);
                t0.u[0] = s0.o0; t1.u[0] = s0.o1; t2.u[0] = s0.o2;
                t0.u[1] = s1.o0; t1.u[1] = s1.o1; t2.u[1] = s1.o2;
                t0.u[2] = s2.o0; t1.u[2] = s2.o1; t2.u[2] = s2.o2;
                t0.u[3] = s3.o0; t1.u[3] = s3.o1; t2.u[3] = s3.o2;
                afr[0][kh][ms] = t0.v;
                afr[1][kh][ms] = t1.v;
                afr[2][kh][ms] = t2.v;
            }
        __syncthreads();
        // prefetch next tile's A f32
        if (k0 + 64 < K) {
#pragma unroll
            for (int kh = 0; kh < 2; ++kh)
#pragma unroll
                for (int ms = 0; ms < 4; ++ms) {
                    av[kh][ms][0] = *(const float4*)(A + aoff[ms] + k0 + 64 + kh * 32);
                    av[kh][ms][1] = *(const float4*)(A + aoff[ms] + k0 + 64 + kh * 32 + 4);
                }
        }
        // 6-term MFMA
#pragma unroll
        for (int kh = 0; kh < 2; ++kh)
#pragma unroll
            for (int pw = 0; pw < 3; ++pw) {
                s8v bf[4];
#pragma unroll
                for (int ns = 0; ns < 4; ++ns)
                    bf[ns] = *(const s8v*)&Blds[pw][kh][bR[ns]][bC[ns]];
#pragma unroll
                for (int pa = 0; pa + pw < 3; ++pa)
#pragma unroll
                    for (int ms = 0; ms < 4; ++ms)
#pragma unroll
                        for (int ns = 0; ns < 4; ++ns)
                            acc[ms][ns] = __builtin_amdgcn_mfma_f32_16x16x32_bf16(
                                afr[pa][kh][ms], bf[ns], acc[ms][ns], 0, 0, 0);
            }
    }

#pragma unroll
    for (int ms = 0; ms < 4; ++ms)
#pragma unroll
        for (int ns = 0; ns < 4; ++ns) {
            const int row = bm + wm * 64 + ms * 16 + quad * 4;
            const int col = bn + wn * 64 + ns * 16 + r16;
#pragma unroll
            for (int r = 0; r < 4; ++r)
                C[(size_t)(row + r) * N + col] = acc[ms][ns][r];
        }
}

// ============ BatchNorm stats — halves MERGED into one dispatch ===========
#define RCHUNK 128

__global__ void bn_stats_partial2(const float* __restrict__ hA,
                                  const float* __restrict__ hB,
                                  float* __restrict__ partial, int N)
{
    const int n = blockIdx.x * 256 + threadIdx.x;
    const int chunk = blockIdx.y;                      // 0..255 global chunk
    const int half = (MM / RCHUNK) / 2;                // 128
    const float* __restrict__ h = (chunk < half) ? hA : hB;
    const int cl = chunk & (half - 1);
    const float* p = h + (size_t)cl * RCHUNK * N + n;
    float s = 0.f, s2 = 0.f;
#pragma unroll 4
    for (int r = 0; r < RCHUNK; ++r) {
        const float v = p[(size_t)r * N];
        s += v;
        s2 = fmaf(v, v, s2);
    }
    partial[((size_t)chunk * 2 + 0) * N + n] = s;
    partial[((size_t)chunk * 2 + 1) * N + n] = s2;
}

__global__ void bn_stats_final(const float* __restrict__ partial,
                               float* __restrict__ stats,
                               int N, int nchunks)
{
    const int n = blockIdx.x * 256 + threadIdx.x;
    double s = 0.0, s2 = 0.0;
    for (int c = 0; c < nchunks; ++c) {
        s  += (double)partial[((size_t)c * 2 + 0) * N + n];
        s2 += (double)partial[((size_t)c * 2 + 1) * N + n];
    }
    const double inv_m = 1.0 / (double)MM;
    const double mu = s * inv_m;
    const double var = s2 * inv_m - mu * mu;
    stats[n]     = (float)mu;
    stats[N + n] = (float)(1.0 / sqrt(var + 1e-5));
}

// ============ fused BN + LIF scan (proven R1 versions) ====================
#define LIF_STEP_PACK(hv)                                            \
    do {                                                             \
        const float hn = ((hv) - mu) * rstd * g + bi;                \
        u = beta * (u - s) + omb * hn;                               \
        const bool sp = (u - 1.0f) >= 0.f;                           \
        s = sp ? 1.f : 0.f;                                          \
        const unsigned long long mball = __ballot(sp);               \
        if (lead) bits[widx] = mball;                                \
        widx += nw;                                                  \
    } while (0)

#define LIF_LOAD8(buf, tbase)                                        \
    _Pragma("unroll")                                                \
    for (int j = 0; j < 8; ++j) {                                    \
        const int tl = (tbase) + j;                                  \
        buf[j] = h[base + (size_t)(tl < TT ? tl : TT - 1) * N];      \
    }

__global__ __launch_bounds__(64) void bn_lif_scan_pack2(
    const float* __restrict__ hA,      // [MHALF, N]  (b < 16)
    const float* __restrict__ hB,      // [MHALF, N]  (b >= 16)
    unsigned long long* __restrict__ bits,
    const float* __restrict__ stats,
    const float* __restrict__ gamma,
    const float* __restrict__ bias,
    const float* __restrict__ beta_p,
    const float* __restrict__ U0,      // [BB, N]
    int N)
{
    const int n = blockIdx.x * 64 + threadIdx.x;
    const int b = blockIdx.y;                       // global batch 0..31
    const float* __restrict__ h = (b < BB / 2) ? hA : hB;
    const int bl = b & (BB / 2 - 1);
    const int nw = N >> 6;
    const float mu = stats[n];
    const float rstd = stats[N + n];
    const float g = gamma[n];
    const float bi = bias[n];
    const float beta = 1.f / (1.f + expf(-beta_p[n]));
    const float omb = 1.f - beta;
    float u = U0[(size_t)b * N + n];
    float s = 0.f;
    const size_t base = ((size_t)bl * TT) * N + n;
    size_t widx = ((size_t)b * TT) * nw + (n >> 6);
    const bool lead = (threadIdx.x & 63) == 0;

    float b0[8], b1[8], b2[8], b3[8];
    LIF_LOAD8(b0, 0);
    LIF_LOAD8(b1, 8);
    LIF_LOAD8(b2, 16);
    for (int t0 = 0; t0 < TT; t0 += 32) {
        LIF_LOAD8(b3, t0 + 24);
#pragma unroll
        for (int j = 0; j < 8; ++j) { const float hv = b0[j]; LIF_STEP_PACK(hv); }
        LIF_LOAD8(b0, t0 + 32);
#pragma unroll
        for (int j = 0; j < 8; ++j) { const float hv = b1[j]; LIF_STEP_PACK(hv); }
        LIF_LOAD8(b1, t0 + 40);
#pragma unroll
        for (int j = 0; j < 8; ++j) { const float hv = b2[j]; LIF_STEP_PACK(hv); }
        LIF_LOAD8(b2, t0 + 48);
#pragma unroll
        for (int j = 0; j < 8; ++j) { const float hv = b3[j]; LIF_STEP_PACK(hv); }
    }
}

#define LIF_STEP_F32(hv)                                             \
    do {                                                             \
        const float hn = ((hv) - mu) * rstd * g + bi;                \
        u = beta * (u - s) + omb * hn;                               \
        s = ((u - 1.0f) >= 0.f) ? 1.f : 0.f;                         \
        out[oidx] = s;                                               \
        oidx += N;                                                   \
    } while (0)

__global__ __launch_bounds__(64) void bn_lif_scan_f32_2(
    const float* __restrict__ h,       // [MM, N] (full)
    float* __restrict__ out,
    const float* __restrict__ stats,
    const float* __restrict__ gamma,
    const float* __restrict__ bias,
    const float* __restrict__ beta_p,
    const float* __restrict__ U0,
    int N)
{
    const int n = blockIdx.x * 64 + threadIdx.x;
    const int b = blockIdx.y;
    const float mu = stats[n];
    const float rstd = stats[N + n];
    const float g = gamma[n];
    const float bi = bias[n];
    const float beta = 1.f / (1.f + expf(-beta_p[n]));
    const float omb = 1.f - beta;
    float u = U0[(size_t)b * N + n];
    float s = 0.f;
    const size_t base = ((size_t)b * TT) * N + n;
    size_t oidx = base;

    float b0[8], b1[8], b2[8], b3[8];
    LIF_LOAD8(b0, 0);
    LIF_LOAD8(b1, 8);
    LIF_LOAD8(b2, 16);
    for (int t0 = 0; t0 < TT; t0 += 32) {
        LIF_LOAD8(b3, t0 + 24);
#pragma unroll
        for (int j = 0; j < 8; ++j) { const float hv = b0[j]; LIF_STEP_F32(hv); }
        LIF_LOAD8(b0, t0 + 32);
#pragma unroll
        for (int j = 0; j < 8; ++j) { const float hv = b1[j]; LIF_STEP_F32(hv); }
        LIF_LOAD8(b1, t0 + 40);
#pragma unroll
        for (int j = 0; j < 8; ++j) { const float hv = b2[j]; LIF_STEP_F32(hv); }
        LIF_LOAD8(b2, t0 + 48);
#pragma unroll
        for (int j = 0; j < 8; ++j) { const float hv = b3[j]; LIF_STEP_F32(hv); }
    }
}

// ============ launcher ====================================================
extern "C" void kernel_launch(void* const* d_in, const int* in_sizes, int n_in,
                              void* d_out, int out_size, void* d_ws, size_t ws_size,
                              hipStream_t stream)
{
    const float* x   = (const float*)d_in[0];
    const float* W1  = (const float*)d_in[1];
    const float* bp1 = (const float*)d_in[2];
    const float* g1  = (const float*)d_in[3];
    const float* bi1 = (const float*)d_in[4];
    const float* U01 = (const float*)d_in[5];
    const float* W2  = (const float*)d_in[6];
    const float* bp2 = (const float*)d_in[7];
    const float* g2  = (const float*)d_in[8];
    const float* bi2 = (const float*)d_in[9];
    const float* U02 = (const float*)d_in[10];
    const float* W3  = (const float*)d_in[11];
    const float* bp3 = (const float*)d_in[12];
    const float* g3  = (const float*)d_in[13];
    const float* bi3 = (const float*)d_in[14];
    const float* U03 = (const float*)d_in[15];
    float* out = (float*)d_out;

    // ws layout (unchanged, ~185 MB): hA | spk | part | stat | W2/W3 planes
    unsigned char* ws = (unsigned char*)d_ws;
    const size_t HA_BYTES  = (size_t)MHALF * HH * sizeof(float);  // 134217728
    const size_t SPK_BYTES = (size_t)MM * (HH / 8);               // 8388608
    float*              hA   = (float*)ws;
    float*              hB   = (float*)d_out;  // scratch until final scan
    unsigned long long* spk  = (unsigned long long*)(ws + HA_BYTES);
    float*              part = (float*)(ws + HA_BYTES + SPK_BYTES);
    float*              stat = (float*)(ws + HA_BYTES + SPK_BYTES + 4194304);
    unsigned short*     W2h  = (unsigned short*)(ws + HA_BYTES + SPK_BYTES + 4194304 + 16384);
    unsigned short*     W2m  = W2h + (size_t)HH * HH;
    unsigned short*     W2l  = W2m + (size_t)HH * HH;
    unsigned short*     W3h  = W2l + (size_t)HH * HH;
    unsigned short*     W3m  = W3h + (size_t)JJ * HH;
    unsigned short*     W3l  = W3m + (size_t)JJ * HH;

    const dim3 blk(256);
    const dim3 blk64(64);
    const dim3 blk512(512);
    const int nck = MM / RCHUNK;       // 256 chunks (global, both halves)

    // ---- Layer 1: x[M,J](f32) * W1[H,J]^T via 6-term bf16x3 MFMA ----
    split_w<<<dim3((HH * JJ) / 256), blk, 0, stream>>>(W1, W2h, W2m, W2l, HH * JJ);
    mfma_f32x3_gemm<<<dim3(HH / 128, MHALF / 128), blk, 0, stream>>>(
        x, W2h, W2m, W2l, hA, MHALF, HH, JJ);
    mfma_f32x3_gemm<<<dim3(HH / 128, MHALF / 128), blk, 0, stream>>>(
        x + (size_t)MHALF * JJ, W2h, W2m, W2l, hB, MHALF, HH, JJ);
    // now W1 planes are dead — split W2/W3 into their home slots
    split_w<<<dim3((HH * HH) / 256), blk, 0, stream>>>(W2, W2h, W2m, W2l, HH * HH);
    split_w<<<dim3((JJ * HH) / 256), blk, 0, stream>>>(W3, W3h, W3m, W3l, JJ * HH);

    bn_stats_partial2<<<dim3(HH / 256, nck), blk, 0, stream>>>(hA, hB, part, HH);
    bn_stats_final<<<dim3(HH / 256), blk, 0, stream>>>(part, stat, HH, nck);
    bn_lif_scan_pack2<<<dim3(HH / 64, BB), blk64, 0, stream>>>(
        hA, hB, spk, stat, g1, bi1, bp1, U01, HH);

    // ---- Layer 2: spk[M,H] * W2[H,H]^T (MFMA bf16x3, 256x128 dbuf) ----
    mfma_spk_gemm<<<dim3(MHALF / 256, HH / 128), blk512, 0, stream>>>(
        (const unsigned char*)spk, W2h, W2m, W2l, hA, MHALF, HH, HH);
    mfma_spk_gemm<<<dim3(MHALF / 256, HH / 128), blk512, 0, stream>>>(
        (const unsigned char*)spk + (size_t)MHALF * (HH / 8), W2h, W2m, W2l, hB, MHALF, HH, HH);
    bn_stats_partial2<<<dim3(HH / 256, nck), blk, 0, stream>>>(hA, hB, part, HH);
    bn_stats_final<<<dim3(HH / 256), blk, 0, stream>>>(part, stat, HH, nck);
    bn_lif_scan_pack2<<<dim3(HH / 64, BB), blk64, 0, stream>>>(
        hA, hB, spk, stat, g2, bi2, bp2, U02, HH);

    // ---- Layer 3: spk[M,H] * W3[J,H]^T -> hA [M,1024] ----
    mfma_spk_gemm<<<dim3(MM / 256, JJ / 128), blk512, 0, stream>>>(
        (const unsigned char*)spk, W3h, W3m, W3l, hA, MM, JJ, HH);
    bn_stats_partial2<<<dim3(JJ / 256, nck), blk, 0, stream>>>(
        hA, hA + (size_t)MHALF * JJ, part, JJ);
    bn_stats_final<<<dim3(JJ / 256), blk, 0, stream>>>(part, stat, JJ, nck);
    bn_lif_scan_f32_2<<<dim3(JJ / 64, BB), blk64, 0, stream>>>(
        hA, out, stat, g3, bi3, bp3, U03, JJ);
}

// Round 5
// 2499.398 us; speedup vs baseline: 1.9351x; 1.0814x over previous
//
#include <hip/hip_runtime.h>
#include <hip/hip_bf16.h>
#include <cmath>

// Problem constants: B=32, T=1024, J=1024, H=2048
#define BB 32
#define TT 1024
#define JJ 1024
#define HH 2048
#define MM (BB * TT)      // 32768 rows
#define MHALF (MM / 2)    // 16384

typedef short s8v __attribute__((ext_vector_type(8)));   // 8 bf16 raw
typedef float f4v __attribute__((ext_vector_type(4)));
typedef unsigned int u4v __attribute__((ext_vector_type(4)));
union ABu { u4v u; s8v v; };

// ============ exact f32 -> bf16 hi/mid/lo (w == h+m+l exactly) ============
__device__ inline void split_bf16x3(float w, unsigned short& h,
                                    unsigned short& m, unsigned short& l) {
    __hip_bfloat16 bh = __float2bfloat16(w);
    const float fh = __bfloat162float(bh);
    const float r1 = w - fh;                  // exact
    __hip_bfloat16 bm = __float2bfloat16(r1);
    const float fm = __bfloat162float(bm);
    __hip_bfloat16 bl = __float2bfloat16(r1 - fm);  // exact residual (8 bits left)
    h = *(unsigned short*)&bh; m = *(unsigned short*)&bm; l = *(unsigned short*)&bl;
}

__global__ void split_w(const float* __restrict__ W,
                        unsigned short* __restrict__ ph,
                        unsigned short* __restrict__ pm,
                        unsigned short* __restrict__ pl, int n)
{
    const int i = blockIdx.x * 256 + threadIdx.x;
    if (i >= n) return;
    split_bf16x3(W[i], ph[i], pm[i], pl[i]);
}

// ============ spike MFMA GEMM — 256x128, 8 waves, dbuf, END-barrier =======
// T3 "minimum 2-phase" schedule: ALL next-tile stages issued at the TOP of
// the K-step, ONE __syncthreads at the END. The implicit vmcnt(0) drain
// then waits on loads covered by ~192 MFMAs -> staging latency hidden.
__global__ __launch_bounds__(512) void mfma_spk_gemm(
    const unsigned char* __restrict__ S,    // [M, K/8] bit-packed spikes
    const unsigned short* __restrict__ Wh,  // [N,K] bf16 raw
    const unsigned short* __restrict__ Wm,
    const unsigned short* __restrict__ Wl,
    float* __restrict__ C, int M, int N, int K)
{
    __shared__ __align__(16) unsigned short Blds[2][3][2][128][32];  // 96 KB
    const int tid = threadIdx.x;
    const int wv = tid >> 6;                 // 0..7
    const int lane = tid & 63;
    const int wm = wv >> 1, wn = wv & 1;     // wm 0..3 (M), wn 0..1 (N)
    const int r16 = lane & 15, quad = lane >> 4;
    const int bm = blockIdx.x * 256;
    const int bn = blockIdx.y * 128;
    const int Kb = K >> 3;

    f4v acc[4][4] = {};

    // staging map: 8 waves x 16 rows = 128 rows per (plane,kh) load
    const int rl = lane >> 2, chl = lane & 3;
    const int srow = wv * 16 + rl;                       // 0..127
    const int kc = (chl - (srow >> 1)) & 3;
    const size_t soff = (size_t)(bn + srow) * K + kc * 8;  // ushort units
    const int ldsrow = wv * 16;

    size_t aoff[4];
#pragma unroll
    for (int ms = 0; ms < 4; ++ms)
        aoff[ms] = (size_t)(bm + wm * 64 + ms * 16 + r16) * Kb + quad;

    int bR[4], bC[4];
#pragma unroll
    for (int ns = 0; ns < 4; ++ns) {
        bR[ns] = wn * 64 + ns * 16 + r16;
        bC[ns] = ((quad + (bR[ns] >> 1)) & 3) * 8;
    }

    auto stage = [&](int buf, int p, int kh, int k0) {
        const unsigned short* Wp = (p == 0) ? Wh : (p == 1) ? Wm : Wl;
        __builtin_amdgcn_global_load_lds(
            (const __attribute__((address_space(1))) void*)(Wp + soff + k0 + kh * 32),
            (__attribute__((address_space(3))) void*)&Blds[buf][p][kh][ldsrow][0], 16, 0, 0);
    };

    // preload first tile's A bytes (k-chunks kh*32: byte offset kh*4)
    unsigned int ab[2][4];
#pragma unroll
    for (int kh = 0; kh < 2; ++kh)
#pragma unroll
        for (int ms = 0; ms < 4; ++ms) ab[kh][ms] = S[aoff[ms] + kh * 4];

    // prologue: stage tile 0 into buffer 0 (6 loads), drain, go
#pragma unroll
    for (int p = 0; p < 3; ++p)
#pragma unroll
        for (int kh = 0; kh < 2; ++kh) stage(0, p, kh, 0);
    __syncthreads();

    const int NT = K >> 6;
    for (int t = 0; t < NT; ++t) {
        const int cur = t & 1, nxt = cur ^ 1;
        const int k0 = t << 6;

        // issue ALL next-tile stages first -> full K-step of latency cover
        if (t + 1 < NT) {
#pragma unroll
            for (int p = 0; p < 3; ++p)
#pragma unroll
                for (int kh = 0; kh < 2; ++kh) stage(nxt, p, kh, k0 + 64);
        }

        // unpack current A bytes -> bf16 fragments (register-only)
        s8v afr[2][4];
#pragma unroll
        for (int kh = 0; kh < 2; ++kh)
#pragma unroll
            for (int ms = 0; ms < 4; ++ms) {
                ABu tu;
                const unsigned int b = ab[kh][ms];
                tu.u[0] = ((b        & 1u) * 0x3F80u) | (((b >> 1) & 1u) * 0x3F800000u);
                tu.u[1] = (((b >> 2) & 1u) * 0x3F80u) | (((b >> 3) & 1u) * 0x3F800000u);
                tu.u[2] = (((b >> 4) & 1u) * 0x3F80u) | (((b >> 5) & 1u) * 0x3F800000u);
                tu.u[3] = (((b >> 6) & 1u) * 0x3F80u) | (((b >> 7) & 1u) * 0x3F800000u);
                afr[kh][ms] = tu.v;
            }
        // prefetch next tile's A bytes (regs consumed -> safe to reload)
        if (t + 1 < NT) {
            const size_t kb = (size_t)((k0 + 64) >> 3);
#pragma unroll
            for (int kh = 0; kh < 2; ++kh)
#pragma unroll
                for (int ms = 0; ms < 4; ++ms) ab[kh][ms] = S[aoff[ms] + kb + kh * 4];
        }

        // 6 phases: {4 ds_read_b128 ; setprio ; 16 MFMA}
#pragma unroll
        for (int p = 0; p < 3; ++p)
#pragma unroll
            for (int kh = 0; kh < 2; ++kh) {
                s8v bf[4];
#pragma unroll
                for (int ns = 0; ns < 4; ++ns)
                    bf[ns] = *(const s8v*)&Blds[cur][p][kh][bR[ns]][bC[ns]];
                __builtin_amdgcn_s_setprio(1);
#pragma unroll
                for (int ms = 0; ms < 4; ++ms)
#pragma unroll
                    for (int ns = 0; ns < 4; ++ns)
                        acc[ms][ns] = __builtin_amdgcn_mfma_f32_16x16x32_bf16(
                            afr[kh][ms], bf[ns], acc[ms][ns], 0, 0, 0);
                __builtin_amdgcn_s_setprio(0);
            }

        // END barrier: drains THIS iter's stages (covered by phases above)
        if (t + 1 < NT) __syncthreads();
    }

#pragma unroll
    for (int ms = 0; ms < 4; ++ms)
#pragma unroll
        for (int ns = 0; ns < 4; ++ns) {
            const int row = bm + wm * 64 + ms * 16 + quad * 4;
            const int col = bn + wn * 64 + ns * 16 + r16;
#pragma unroll
            for (int r = 0; r < 4; ++r)
                C[(size_t)(row + r) * N + col] = acc[ms][ns][r];
        }
}

// ============ f32-via-bf16x3 MFMA GEMM — NEW: dbuf BK=32, END-barrier =====
// Same exact 6-term arithmetic as R3 (absmax 0.0); only the tile schedule
// changed: BK=32, double-buffered 48 KB LDS (3 blocks/CU), stages at top,
// one barrier at end of each K-step.
struct Sp3 { unsigned int o0, o1, o2; };

__device__ inline Sp3 split_pair(float x, float y)
{
    const unsigned int xb = __float_as_uint(x), yb = __float_as_uint(y);
    const unsigned int x0 = xb & 0xFFFF0000u,  y0 = yb & 0xFFFF0000u;
    const float xr1 = x - __uint_as_float(x0), yr1 = y - __uint_as_float(y0);
    const unsigned int x1b = __float_as_uint(xr1), y1b = __float_as_uint(yr1);
    const unsigned int x1 = x1b & 0xFFFF0000u, y1 = y1b & 0xFFFF0000u;
    const float xr2 = xr1 - __uint_as_float(x1), yr2 = yr1 - __uint_as_float(y1);
    Sp3 r;
    // pack bf16 pair (x in low16, y in high16) = bytes [x.b2,x.b3,y.b2,y.b3]
    r.o0 = __builtin_amdgcn_perm(yb, xb, 0x07060302u);
    r.o1 = __builtin_amdgcn_perm(y1b, x1b, 0x07060302u);
    r.o2 = __builtin_amdgcn_perm(__float_as_uint(yr2), __float_as_uint(xr2), 0x07060302u);
    return r;
}

__global__ __launch_bounds__(256) void mfma_f32x3_gemm(
    const float* __restrict__ A,            // [M,K] f32
    const unsigned short* __restrict__ Wh,  // [N,K] bf16 planes (exact sum)
    const unsigned short* __restrict__ Wm,
    const unsigned short* __restrict__ Wl,
    float* __restrict__ C, int M, int N, int K)
{
    __shared__ __align__(16) unsigned short Blds[2][3][128][32];  // 48 KB dbuf
    const int tid = threadIdx.x;
    const int wv = tid >> 6;
    const int lane = tid & 63;
    const int wm = wv >> 1, wn = wv & 1;
    const int r16 = lane & 15, quad = lane >> 4;

    // XCD-chunked panel swizzle (proven R3): 16 N-blocks of one M-panel on
    // one XCD, temporally adjacent -> A-panel read ~once into that L2.
    const int lin = blockIdx.y * 16 + blockIdx.x;   // dispatch-order index
    const int ppx = gridDim.y >> 3;                 // M-panels per XCD
    const int xcd = lin & 7, li = lin >> 3;
    const int pm = xcd * ppx + (li >> 4);
    const int pn = li & 15;
    const int bm = pm * 128;
    const int bn = pn * 128;

    f4v acc[4][4] = {};

    // staging map: 2 issues per plane cover 128 rows x 32 cols (BK=32)
    const int rl = lane >> 2, chl = lane & 3;
    size_t soff[2];
    int ldsrow[2];
#pragma unroll
    for (int i = 0; i < 2; ++i) {
        const int r = i * 64 + wv * 16 + rl;           // 0..127
        const int kc = (chl - (r >> 1)) & 3;
        soff[i] = (size_t)(bn + r) * K + kc * 8;       // ushort units
        ldsrow[i] = i * 64 + wv * 16;
    }

    size_t aoff[4];
#pragma unroll
    for (int ms = 0; ms < 4; ++ms)
        aoff[ms] = (size_t)(bm + wm * 64 + ms * 16 + r16) * K + quad * 8;  // f32

    int bR[4], bC[4];
#pragma unroll
    for (int ns = 0; ns < 4; ++ns) {
        bR[ns] = wn * 64 + ns * 16 + r16;
        bC[ns] = ((quad + (bR[ns] >> 1)) & 3) * 8;
    }

    auto stage = [&](int buf, int p, int i, int k0) {
        const unsigned short* Wp = (p == 0) ? Wh : (p == 1) ? Wm : Wl;
        __builtin_amdgcn_global_load_lds(
            (const __attribute__((address_space(1))) void*)(Wp + soff[i] + k0),
            (__attribute__((address_space(3))) void*)&Blds[buf][p][ldsrow[i]][0], 16, 0, 0);
    };

    // prologue: A f32 for tile 0 (8 elems per ms) + stage tile 0 -> buf 0
    float4 av[4][2];
#pragma unroll
    for (int ms = 0; ms < 4; ++ms) {
        av[ms][0] = *(const float4*)(A + aoff[ms]);
        av[ms][1] = *(const float4*)(A + aoff[ms] + 4);
    }
#pragma unroll
    for (int p = 0; p < 3; ++p)
#pragma unroll
        for (int i = 0; i < 2; ++i) stage(0, p, i, 0);
    __syncthreads();

    const int NT = K >> 5;   // BK=32
    for (int t = 0; t < NT; ++t) {
        const int cur = t & 1, nxt = cur ^ 1;
        const int k0 = t << 5;

        // issue next-tile B stages first (full K-step of cover)
        if (t + 1 < NT) {
#pragma unroll
            for (int p = 0; p < 3; ++p)
#pragma unroll
                for (int i = 0; i < 2; ++i) stage(nxt, p, i, k0 + 32);
        }

        // split current A f32 -> 3 bf16 plane fragments (register-only)
        s8v afr[3][4];
#pragma unroll
        for (int ms = 0; ms < 4; ++ms) {
            ABu t0, t1, t2;
            const float4 v0 = av[ms][0];
            const float4 v1 = av[ms][1];
            const Sp3 s0 = split_pair(v0.x, v0.y);
            const Sp3 s1 = split_pair(v0.z, v0.w);
            const Sp3 s2 = split_pair(v1.x, v1.y);
            const Sp3 s3 = split_pair(v1.z, v1.w);
            t0.u[0] = s0.o0; t1.u[0] = s0.o1; t2.u[0] = s0.o2;
            t0.u[1] = s1.o0; t1.u[1] = s1.o1; t2.u[1] = s1.o2;
            t0.u[2] = s2.o0; t1.u[2] = s2.o1; t2.u[2] = s2.o2;
            t0.u[3] = s3.o0; t1.u[3] = s3.o1; t2.u[3] = s3.o2;
            afr[0][ms] = t0.v;
            afr[1][ms] = t1.v;
            afr[2][ms] = t2.v;
        }
        // av consumed -> reload with next tile's A (single-buffered regs)
        if (t + 1 < NT) {
#pragma unroll
            for (int ms = 0; ms < 4; ++ms) {
                av[ms][0] = *(const float4*)(A + aoff[ms] + k0 + 32);
                av[ms][1] = *(const float4*)(A + aoff[ms] + k0 + 32 + 4);
            }
        }

        // 3 phases by W-plane: {4 ds_read_b128 ; MFMA terms pa+pw<3}
#pragma unroll
        for (int pw = 0; pw < 3; ++pw) {
            s8v bf[4];
#pragma unroll
            for (int ns = 0; ns < 4; ++ns)
                bf[ns] = *(const s8v*)&Blds[cur][pw][bR[ns]][bC[ns]];
            __builtin_amdgcn_s_setprio(1);
#pragma unroll
            for (int pa = 0; pa + pw < 3; ++pa)
#pragma unroll
                for (int ms = 0; ms < 4; ++ms)
#pragma unroll
                    for (int ns = 0; ns < 4; ++ns)
                        acc[ms][ns] = __builtin_amdgcn_mfma_f32_16x16x32_bf16(
                            afr[pa][ms], bf[ns], acc[ms][ns], 0, 0, 0);
            __builtin_amdgcn_s_setprio(0);
        }

        if (t + 1 < NT) __syncthreads();
    }

#pragma unroll
    for (int ms = 0; ms < 4; ++ms)
#pragma unroll
        for (int ns = 0; ns < 4; ++ns) {
            const int row = bm + wm * 64 + ms * 16 + quad * 4;
            const int col = bn + wn * 64 + ns * 16 + r16;
#pragma unroll
            for (int r = 0; r < 4; ++r)
                C[(size_t)(row + r) * N + col] = acc[ms][ns][r];
        }
}

// ============ BatchNorm stats — halves MERGED into one dispatch ===========
#define RCHUNK 128

__global__ void bn_stats_partial2(const float* __restrict__ hA,
                                  const float* __restrict__ hB,
                                  float* __restrict__ partial, int N)
{
    const int n = blockIdx.x * 256 + threadIdx.x;
    const int chunk = blockIdx.y;                      // 0..255 global chunk
    const int half = (MM / RCHUNK) / 2;                // 128
    const float* __restrict__ h = (chunk < half) ? hA : hB;
    const int cl = chunk & (half - 1);
    const float* p = h + (size_t)cl * RCHUNK * N + n;
    float s = 0.f, s2 = 0.f;
#pragma unroll 4
    for (int r = 0; r < RCHUNK; ++r) {
        const float v = p[(size_t)r * N];
        s += v;
        s2 = fmaf(v, v, s2);
    }
    partial[((size_t)chunk * 2 + 0) * N + n] = s;
    partial[((size_t)chunk * 2 + 1) * N + n] = s2;
}

__global__ void bn_stats_final(const float* __restrict__ partial,
                               float* __restrict__ stats,
                               int N, int nchunks)
{
    const int n = blockIdx.x * 256 + threadIdx.x;
    double s = 0.0, s2 = 0.0;
    for (int c = 0; c < nchunks; ++c) {
        s  += (double)partial[((size_t)c * 2 + 0) * N + n];
        s2 += (double)partial[((size_t)c * 2 + 1) * N + n];
    }
    const double inv_m = 1.0 / (double)MM;
    const double mu = s * inv_m;
    const double var = s2 * inv_m - mu * mu;
    stats[n]     = (float)mu;
    stats[N + n] = (float)(1.0 / sqrt(var + 1e-5));
}

// ============ fused BN + LIF scan (proven R1 versions) ====================
#define LIF_STEP_PACK(hv)                                            \
    do {                                                             \
        const float hn = ((hv) - mu) * rstd * g + bi;                \
        u = beta * (u - s) + omb * hn;                               \
        const bool sp = (u - 1.0f) >= 0.f;                           \
        s = sp ? 1.f : 0.f;                                          \
        const unsigned long long mball = __ballot(sp);               \
        if (lead) bits[widx] = mball;                                \
        widx += nw;                                                  \
    } while (0)

#define LIF_LOAD8(buf, tbase)                                        \
    _Pragma("unroll")                                                \
    for (int j = 0; j < 8; ++j) {                                    \
        const int tl = (tbase) + j;                                  \
        buf[j] = h[base + (size_t)(tl < TT ? tl : TT - 1) * N];      \
    }

__global__ __launch_bounds__(64) void bn_lif_scan_pack2(
    const float* __restrict__ hA,      // [MHALF, N]  (b < 16)
    const float* __restrict__ hB,      // [MHALF, N]  (b >= 16)
    unsigned long long* __restrict__ bits,
    const float* __restrict__ stats,
    const float* __restrict__ gamma,
    const float* __restrict__ bias,
    const float* __restrict__ beta_p,
    const float* __restrict__ U0,      // [BB, N]
    int N)
{
    const int n = blockIdx.x * 64 + threadIdx.x;
    const int b = blockIdx.y;                       // global batch 0..31
    const float* __restrict__ h = (b < BB / 2) ? hA : hB;
    const int bl = b & (BB / 2 - 1);
    const int nw = N >> 6;
    const float mu = stats[n];
    const float rstd = stats[N + n];
    const float g = gamma[n];
    const float bi = bias[n];
    const float beta = 1.f / (1.f + expf(-beta_p[n]));
    const float omb = 1.f - beta;
    float u = U0[(size_t)b * N + n];
    float s = 0.f;
    const size_t base = ((size_t)bl * TT) * N + n;
    size_t widx = ((size_t)b * TT) * nw + (n >> 6);
    const bool lead = (threadIdx.x & 63) == 0;

    float b0[8], b1[8], b2[8], b3[8];
    LIF_LOAD8(b0, 0);
    LIF_LOAD8(b1, 8);
    LIF_LOAD8(b2, 16);
    for (int t0 = 0; t0 < TT; t0 += 32) {
        LIF_LOAD8(b3, t0 + 24);
#pragma unroll
        for (int j = 0; j < 8; ++j) { const float hv = b0[j]; LIF_STEP_PACK(hv); }
        LIF_LOAD8(b0, t0 + 32);
#pragma unroll
        for (int j = 0; j < 8; ++j) { const float hv = b1[j]; LIF_STEP_PACK(hv); }
        LIF_LOAD8(b1, t0 + 40);
#pragma unroll
        for (int j = 0; j < 8; ++j) { const float hv = b2[j]; LIF_STEP_PACK(hv); }
        LIF_LOAD8(b2, t0 + 48);
#pragma unroll
        for (int j = 0; j < 8; ++j) { const float hv = b3[j]; LIF_STEP_PACK(hv); }
    }
}

#define LIF_STEP_F32(hv)                                             \
    do {                                                             \
        const float hn = ((hv) - mu) * rstd * g + bi;                \
        u = beta * (u - s) + omb * hn;                               \
        s = ((u - 1.0f) >= 0.f) ? 1.f : 0.f;                         \
        out[oidx] = s;                                               \
        oidx += N;                                                   \
    } while (0)

__global__ __launch_bounds__(64) void bn_lif_scan_f32_2(
    const float* __restrict__ h,       // [MM, N] (full)
    float* __restrict__ out,
    const float* __restrict__ stats,
    const float* __restrict__ gamma,
    const float* __restrict__ bias,
    const float* __restrict__ beta_p,
    const float* __restrict__ U0,
    int N)
{
    const int n = blockIdx.x * 64 + threadIdx.x;
    const int b = blockIdx.y;
    const float mu = stats[n];
    const float rstd = stats[N + n];
    const float g = gamma[n];
    const float bi = bias[n];
    const float beta = 1.f / (1.f + expf(-beta_p[n]));
    const float omb = 1.f - beta;
    float u = U0[(size_t)b * N + n];
    float s = 0.f;
    const size_t base = ((size_t)b * TT) * N + n;
    size_t oidx = base;

    float b0[8], b1[8], b2[8], b3[8];
    LIF_LOAD8(b0, 0);
    LIF_LOAD8(b1, 8);
    LIF_LOAD8(b2, 16);
    for (int t0 = 0; t0 < TT; t0 += 32) {
        LIF_LOAD8(b3, t0 + 24);
#pragma unroll
        for (int j = 0; j < 8; ++j) { const float hv = b0[j]; LIF_STEP_F32(hv); }
        LIF_LOAD8(b0, t0 + 32);
#pragma unroll
        for (int j = 0; j < 8; ++j) { const float hv = b1[j]; LIF_STEP_F32(hv); }
        LIF_LOAD8(b1, t0 + 40);
#pragma unroll
        for (int j = 0; j < 8; ++j) { const float hv = b2[j]; LIF_STEP_F32(hv); }
        LIF_LOAD8(b2, t0 + 48);
#pragma unroll
        for (int j = 0; j < 8; ++j) { const float hv = b3[j]; LIF_STEP_F32(hv); }
    }
}

// ============ launcher ====================================================
extern "C" void kernel_launch(void* const* d_in, const int* in_sizes, int n_in,
                              void* d_out, int out_size, void* d_ws, size_t ws_size,
                              hipStream_t stream)
{
    const float* x   = (const float*)d_in[0];
    const float* W1  = (const float*)d_in[1];
    const float* bp1 = (const float*)d_in[2];
    const float* g1  = (const float*)d_in[3];
    const float* bi1 = (const float*)d_in[4];
    const float* U01 = (const float*)d_in[5];
    const float* W2  = (const float*)d_in[6];
    const float* bp2 = (const float*)d_in[7];
    const float* g2  = (const float*)d_in[8];
    const float* bi2 = (const float*)d_in[9];
    const float* U02 = (const float*)d_in[10];
    const float* W3  = (const float*)d_in[11];
    const float* bp3 = (const float*)d_in[12];
    const float* g3  = (const float*)d_in[13];
    const float* bi3 = (const float*)d_in[14];
    const float* U03 = (const float*)d_in[15];
    float* out = (float*)d_out;

    // ws layout (unchanged, ~185 MB): hA | spk | part | stat | W2/W3 planes
    unsigned char* ws = (unsigned char*)d_ws;
    const size_t HA_BYTES  = (size_t)MHALF * HH * sizeof(float);  // 134217728
    const size_t SPK_BYTES = (size_t)MM * (HH / 8);               // 8388608
    float*              hA   = (float*)ws;
    float*              hB   = (float*)d_out;  // scratch until final scan
    unsigned long long* spk  = (unsigned long long*)(ws + HA_BYTES);
    float*              part = (float*)(ws + HA_BYTES + SPK_BYTES);
    float*              stat = (float*)(ws + HA_BYTES + SPK_BYTES + 4194304);
    unsigned short*     W2h  = (unsigned short*)(ws + HA_BYTES + SPK_BYTES + 4194304 + 16384);
    unsigned short*     W2m  = W2h + (size_t)HH * HH;
    unsigned short*     W2l  = W2m + (size_t)HH * HH;
    unsigned short*     W3h  = W2l + (size_t)HH * HH;
    unsigned short*     W3m  = W3h + (size_t)JJ * HH;
    unsigned short*     W3l  = W3m + (size_t)JJ * HH;

    const dim3 blk(256);
    const dim3 blk64(64);
    const dim3 blk512(512);
    const int nck = MM / RCHUNK;       // 256 chunks (global, both halves)

    // ---- Layer 1: x[M,J](f32) * W1[H,J]^T via 6-term bf16x3 MFMA ----
    split_w<<<dim3((HH * JJ) / 256), blk, 0, stream>>>(W1, W2h, W2m, W2l, HH * JJ);
    mfma_f32x3_gemm<<<dim3(HH / 128, MHALF / 128), blk, 0, stream>>>(
        x, W2h, W2m, W2l, hA, MHALF, HH, JJ);
    mfma_f32x3_gemm<<<dim3(HH / 128, MHALF / 128), blk, 0, stream>>>(
        x + (size_t)MHALF * JJ, W2h, W2m, W2l, hB, MHALF, HH, JJ);
    // now W1 planes are dead — split W2/W3 into their home slots
    split_w<<<dim3((HH * HH) / 256), blk, 0, stream>>>(W2, W2h, W2m, W2l, HH * HH);
    split_w<<<dim3((JJ * HH) / 256), blk, 0, stream>>>(W3, W3h, W3m, W3l, JJ * HH);

    bn_stats_partial2<<<dim3(HH / 256, nck), blk, 0, stream>>>(hA, hB, part, HH);
    bn_stats_final<<<dim3(HH / 256), blk, 0, stream>>>(part, stat, HH, nck);
    bn_lif_scan_pack2<<<dim3(HH / 64, BB), blk64, 0, stream>>>(
        hA, hB, spk, stat, g1, bi1, bp1, U01, HH);

    // ---- Layer 2: spk[M,H] * W2[H,H]^T (MFMA bf16x3, 256x128 dbuf) ----
    mfma_spk_gemm<<<dim3(MHALF / 256, HH / 128), blk512, 0, stream>>>(
        (const unsigned char*)spk, W2h, W2m, W2l, hA, MHALF, HH, HH);
    mfma_spk_gemm<<<dim3(MHALF / 256, HH / 128), blk512, 0, stream>>>(
        (const unsigned char*)spk + (size_t)MHALF * (HH / 8), W2h, W2m, W2l, hB, MHALF, HH, HH);
    bn_stats_partial2<<<dim3(HH / 256, nck), blk, 0, stream>>>(hA, hB, part, HH);
    bn_stats_final<<<dim3(HH / 256), blk, 0, stream>>>(part, stat, HH, nck);
    bn_lif_scan_pack2<<<dim3(HH / 64, BB), blk64, 0, stream>>>(
        hA, hB, spk, stat, g2, bi2, bp2, U02, HH);

    // ---- Layer 3: spk[M,H] * W3[J,H]^T -> hA [M,1024] ----
    mfma_spk_gemm<<<dim3(MM / 256, JJ / 128), blk512, 0, stream>>>(
        (const unsigned char*)spk, W3h, W3m, W3l, hA, MM, JJ, HH);
    bn_stats_partial2<<<dim3(JJ / 256, nck), blk, 0, stream>>>(
        hA, hA + (size_t)MHALF * JJ, part, JJ);
    bn_stats_final<<<dim3(JJ / 256), blk, 0, stream>>>(part, stat, JJ, nck);
    bn_lif_scan_f32_2<<<dim3(JJ / 64, BB), blk64, 0, stream>>>(
        hA, out, stat, g3, bi3, bp3, U03, JJ);
}